// Round 6
// baseline (11981.999 us; speedup 1.0000x reference)
//
#include <hip/hip_runtime.h>
#include <hip/hip_bf16.h>

typedef unsigned char u8;

static constexpr int SEQ = 512;
static constexpr int NB  = 64;
static constexpr int HID = 512;
static constexpr int HD  = 256;
static constexpr int NT  = 9;
static constexpr int NV  = 21128;

static __device__ __forceinline__ float sigm(float x) { return 1.0f / (1.0f + __expf(-x)); }

// ---------------------------------------------------------------------------
// K1: P[v, g] = sum_h E[v,h] * W[g,h] + bih[g]   (both directions)
// ---------------------------------------------------------------------------
__global__ __launch_bounds__(256)
void k_proj(const float* __restrict__ E, const float* __restrict__ Wf, const float* __restrict__ bf,
            const float* __restrict__ Wb, const float* __restrict__ bb,
            float* __restrict__ Pf, float* __restrict__ Pb)
{
    __shared__ float As[32][72];
    __shared__ float Bs[32][136];
    const int gx = blockIdx.x;
    const int vb = blockIdx.y * 64;
    const float* W; const float* bias; float* P; int gl0;
    if (gx < 6) { W = Wf; bias = bf; P = Pf; gl0 = gx * 128; }
    else        { W = Wb; bias = bb; P = Pb; gl0 = (gx - 6) * 128; }
    const int tid = threadIdx.x;
    const int tx = tid & 15, ty = tid >> 4;
    float acc[4][8];
#pragma unroll
    for (int i = 0; i < 4; ++i)
#pragma unroll
        for (int j = 0; j < 8; ++j) acc[i][j] = 0.f;

    for (int kt = 0; kt < HID; kt += 32) {
#pragma unroll
        for (int i = 0; i < 2; ++i) {
            int f = tid + i * 256;
            int r = f >> 3, kc = (f & 7) * 4;
            int row = vb + r; if (row >= NV) row = NV - 1;
            float4 v = *(const float4*)(E + (size_t)row * HID + kt + kc);
            As[kc + 0][r] = v.x; As[kc + 1][r] = v.y; As[kc + 2][r] = v.z; As[kc + 3][r] = v.w;
        }
#pragma unroll
        for (int i = 0; i < 4; ++i) {
            int f = tid + i * 256;
            int c = f >> 3, kc = (f & 7) * 4;
            float4 v = *(const float4*)(W + (size_t)(gl0 + c) * HID + kt + kc);
            Bs[kc + 0][c] = v.x; Bs[kc + 1][c] = v.y; Bs[kc + 2][c] = v.z; Bs[kc + 3][c] = v.w;
        }
        __syncthreads();
#pragma unroll
        for (int k = 0; k < 32; ++k) {
            float4 a  = *(const float4*)&As[k][ty * 4];
            float4 b0 = *(const float4*)&Bs[k][tx * 8];
            float4 b1 = *(const float4*)&Bs[k][tx * 8 + 4];
            float av[4] = { a.x, a.y, a.z, a.w };
            float bv[8] = { b0.x, b0.y, b0.z, b0.w, b1.x, b1.y, b1.z, b1.w };
#pragma unroll
            for (int i = 0; i < 4; ++i)
#pragma unroll
                for (int j = 0; j < 8; ++j) acc[i][j] = fmaf(av[i], bv[j], acc[i][j]);
        }
        __syncthreads();
    }
#pragma unroll
    for (int i = 0; i < 4; ++i) {
        int row = vb + ty * 4 + i;
        if (row < NV) {
#pragma unroll
            for (int j = 0; j < 8; ++j) {
                int gc = gl0 + tx * 8 + j;
                P[(size_t)row * 768 + gc] = acc[i][j] + bias[gc];
            }
        }
    }
}

// ---------------------------------------------------------------------------
// K2: GRU recurrence, 64 WGs = 32 batch-pairs x 2 directions
// ---------------------------------------------------------------------------
__global__ __launch_bounds__(256)
void k_gru(const float* __restrict__ Pf, const float* __restrict__ Pb,
           const int* __restrict__ src,
           const float* __restrict__ Whh_f, const float* __restrict__ Whh_b,
           const float* __restrict__ bhh_f, const float* __restrict__ bhh_b,
           float* __restrict__ hf, float* __restrict__ hb)
{
    __shared__ float hsm[2][HD];
    const int w = blockIdx.x;
    const int dir = w & 1;
    const int pr = w >> 1;
    const int b0 = pr * 2, b1 = b0 + 1;
    const float* Whh = dir ? Whh_b : Whh_f;
    const float* bhh = dir ? bhh_b : bhh_f;
    const float* P   = dir ? Pb : Pf;
    float* hout      = dir ? hb : hf;
    const int t = threadIdx.x;
    hsm[0][t] = 0.f; hsm[1][t] = 0.f;
    float h0 = 0.f, h1 = 0.f;
    const float bh_r = bhh[t], bh_z = bhh[HD + t], bh_n = bhh[2 * HD + t];
    const float4* wr = (const float4*)(Whh + (size_t)t * HD);
    const float4* wz = (const float4*)(Whh + (size_t)(HD + t) * HD);
    const float4* wn = (const float4*)(Whh + (size_t)(2 * HD + t) * HD);
    __syncthreads();

    for (int i = 0; i < SEQ; ++i) {
        const int s = dir ? (SEQ - 1 - i) : i;
        const int tok0 = src[b0 * SEQ + s];
        const int tok1 = src[b1 * SEQ + s];
        const float xr0 = P[(size_t)tok0 * 768 + t];
        const float xz0 = P[(size_t)tok0 * 768 + HD + t];
        const float xn0 = P[(size_t)tok0 * 768 + 2 * HD + t];
        const float xr1 = P[(size_t)tok1 * 768 + t];
        const float xz1 = P[(size_t)tok1 * 768 + HD + t];
        const float xn1 = P[(size_t)tok1 * 768 + 2 * HD + t];

        float ar0 = 0.f, az0 = 0.f, an0 = 0.f, ar1 = 0.f, az1 = 0.f, an1 = 0.f;
        const float4* h0p = (const float4*)hsm[0];
        const float4* h1p = (const float4*)hsm[1];
#pragma unroll 4
        for (int k = 0; k < HD / 4; ++k) {
            float4 ha = h0p[k], hc = h1p[k];
            float4 w1 = wr[k], w2 = wz[k], w3 = wn[k];
            ar0 = fmaf(ha.x, w1.x, ar0); ar0 = fmaf(ha.y, w1.y, ar0); ar0 = fmaf(ha.z, w1.z, ar0); ar0 = fmaf(ha.w, w1.w, ar0);
            az0 = fmaf(ha.x, w2.x, az0); az0 = fmaf(ha.y, w2.y, az0); az0 = fmaf(ha.z, w2.z, az0); az0 = fmaf(ha.w, w2.w, az0);
            an0 = fmaf(ha.x, w3.x, an0); an0 = fmaf(ha.y, w3.y, an0); an0 = fmaf(ha.z, w3.z, an0); an0 = fmaf(ha.w, w3.w, an0);
            ar1 = fmaf(hc.x, w1.x, ar1); ar1 = fmaf(hc.y, w1.y, ar1); ar1 = fmaf(hc.z, w1.z, ar1); ar1 = fmaf(hc.w, w1.w, ar1);
            az1 = fmaf(hc.x, w2.x, az1); az1 = fmaf(hc.y, w2.y, az1); az1 = fmaf(hc.z, w2.z, az1); az1 = fmaf(hc.w, w2.w, az1);
            an1 = fmaf(hc.x, w3.x, an1); an1 = fmaf(hc.y, w3.y, an1); an1 = fmaf(hc.z, w3.z, an1); an1 = fmaf(hc.w, w3.w, an1);
        }
        __syncthreads();

        float r0 = sigm(xr0 + ar0 + bh_r);
        float z0 = sigm(xz0 + az0 + bh_z);
        float n0 = tanhf(xn0 + r0 * (an0 + bh_n));
        h0 = (1.f - z0) * n0 + z0 * h0;
        float r1 = sigm(xr1 + ar1 + bh_r);
        float z1 = sigm(xz1 + az1 + bh_z);
        float n1 = tanhf(xn1 + r1 * (an1 + bh_n));
        h1 = (1.f - z1) * n1 + z1 * h1;

        hsm[0][t] = h0; hsm[1][t] = h1;
        __syncthreads();

        size_t base = ((size_t)s * NB + b0) * HD + t;
        hout[base] = h0;
        hout[base + HD] = h1;
    }
}

// ---------------------------------------------------------------------------
// K3: logits[b][s][t] = [hf|hb] . outW[t] + outb[t]   (stored [B][S][T] f32)
// ---------------------------------------------------------------------------
__global__ __launch_bounds__(256)
void k_logits(const float* __restrict__ hf, const float* __restrict__ hb,
              const float* __restrict__ outW, const float* __restrict__ outb,
              float* __restrict__ logitsB)
{
    __shared__ float Wsm[NT][HID];
    __shared__ float bsm[NT];
    const int tid = threadIdx.x;
    for (int i = tid; i < NT * HID; i += 256) Wsm[i >> 9][i & 511] = outW[i];
    if (tid < NT) bsm[tid] = outb[tid];
    __syncthreads();

    const int sb = blockIdx.x * 256 + tid;   // sb = s*64 + b
    const int s = sb >> 6, b = sb & 63;
    float acc[NT];
#pragma unroll
    for (int t = 0; t < NT; ++t) acc[t] = bsm[t];
    const float4* hfp = (const float4*)(hf + (size_t)sb * HD);
    const float4* hbp = (const float4*)(hb + (size_t)sb * HD);
#pragma unroll 4
    for (int k4 = 0; k4 < HD / 4; ++k4) {
        float4 hv = hfp[k4];
#pragma unroll
        for (int t = 0; t < NT; ++t) {
            float4 wv = *(const float4*)&Wsm[t][k4 * 4];
            acc[t] = fmaf(hv.x, wv.x, fmaf(hv.y, wv.y, fmaf(hv.z, wv.z, fmaf(hv.w, wv.w, acc[t]))));
        }
    }
#pragma unroll 4
    for (int k4 = 0; k4 < HD / 4; ++k4) {
        float4 hv = hbp[k4];
#pragma unroll
        for (int t = 0; t < NT; ++t) {
            float4 wv = *(const float4*)&Wsm[t][HD + k4 * 4];
            acc[t] = fmaf(hv.x, wv.x, fmaf(hv.y, wv.y, fmaf(hv.z, wv.z, fmaf(hv.w, wv.w, acc[t]))));
        }
    }
    float* out = logitsB + ((size_t)b * SEQ + s) * NT;
#pragma unroll
    for (int t = 0; t < NT; ++t) out[t] = acc[t];
}

// ---------------------------------------------------------------------------
// K4: CRF forward (logsumexp) + Viterbi + gold score, one wave per batch
// ---------------------------------------------------------------------------
__global__ __launch_bounds__(64)
void k_crf(const float* __restrict__ logitsB, const int* __restrict__ label,
           const float* __restrict__ startv, const float* __restrict__ endv,
           const float* __restrict__ trans,
           int* __restrict__ predict, float* __restrict__ llh)
{
    __shared__ u8 hist[(SEQ - 1) * NT + 16];
    const int b = blockIdx.x;
    const int l = threadIdx.x;
    const float* em = logitsB + (size_t)b * SEQ * NT;
    const int* lab = label + b * SEQ;

    float tr[NT];
#pragma unroll
    for (int t = 0; t < NT; ++t) tr[t] = (l < NT) ? trans[t * NT + l] : 0.f;

    float numacc = 0.f;
    for (int j = 0; j < 8; ++j) {
        int s = l + j * 64;
        int ls = lab[s];
        numacc += em[s * NT + ls];
        if (s < SEQ - 1) numacc += trans[ls * NT + lab[s + 1]];
        if (s == 0) numacc += startv[ls];
        if (s == SEQ - 1) numacc += endv[ls];
    }
#pragma unroll
    for (int off = 32; off > 0; off >>= 1) numacc += __shfl_down(numacc, off);

    float sc = 0.f, vs = 0.f;
    if (l < NT) { sc = startv[l] + em[l]; vs = sc; }
    float emn = (l < NT) ? em[NT + l] : 0.f;
    for (int s = 1; s < SEQ; ++s) {
        float emc = emn;
        if (s < SEQ - 1) emn = (l < NT) ? em[(s + 1) * NT + l] : 0.f;
        float psv[NT], pvv[NT];
#pragma unroll
        for (int t = 0; t < NT; ++t) {
            psv[t] = __shfl(sc, t) + tr[t];
            pvv[t] = __shfl(vs, t) + tr[t];
        }
        float bestv = pvv[0]; int barg = 0;
#pragma unroll
        for (int t = 1; t < NT; ++t) { if (pvv[t] > bestv) { bestv = pvv[t]; barg = t; } }
        float m = psv[0];
#pragma unroll
        for (int t = 1; t < NT; ++t) m = fmaxf(m, psv[t]);
        float ssum = 0.f;
#pragma unroll
        for (int t = 0; t < NT; ++t) ssum += __expf(psv[t] - m);
        if (l < NT) hist[(s - 1) * NT + l] = (u8)barg;
        sc = m + __logf(ssum) + emc;
        vs = bestv + emc;
    }

    float scg[NT], vsg[NT];
#pragma unroll
    for (int t = 0; t < NT; ++t) {
        scg[t] = __shfl(sc, t) + endv[t];
        vsg[t] = __shfl(vs, t) + endv[t];
    }
    float mm = scg[0];
#pragma unroll
    for (int t = 1; t < NT; ++t) mm = fmaxf(mm, scg[t]);
    float sm = 0.f;
#pragma unroll
    for (int t = 0; t < NT; ++t) sm += __expf(scg[t] - mm);
    float den = mm + __logf(sm);
    float bv = vsg[0]; int last = 0;
#pragma unroll
    for (int t = 1; t < NT; ++t) { if (vsg[t] > bv) { bv = vsg[t]; last = t; } }

    if (l == 0) llh[b] = numacc - den;
    __syncthreads();
    if (l == 0) {
        int cur = last;
        predict[b * SEQ + (SEQ - 1)] = cur;
        for (int s = SEQ - 2; s >= 0; --s) {
            cur = hist[s * NT + cur];
            predict[b * SEQ + s] = cur;
        }
    }
}

// ---------------------------------------------------------------------------
__global__ void k_init(int* c, float* llh)
{
    if (threadIdx.x == 0) *c = 0;
    if (threadIdx.x < NB) llh[threadIdx.x] = 0.f;
}

// out is FLOAT32: [0]=loss, [1]=correct, [2..32770)=predict, [32770..65538)=label
__global__ __launch_bounds__(256)
void k_final(const int* __restrict__ label, const int* __restrict__ predict,
             float* __restrict__ out, int* __restrict__ correct)
{
    int i = blockIdx.x * 256 + threadIdx.x;   // 0..32767 = b*512+s
    int lb = label[i];
    int pd = (lb > 0) ? predict[i] : 0;
    out[2 + i] = (float)pd;
    out[2 + NB * SEQ + i] = (float)lb;
    int c = (pd == lb) ? 1 : 0;
#pragma unroll
    for (int off = 32; off > 0; off >>= 1) c += __shfl_down(c, off);
    if ((threadIdx.x & 63) == 0) atomicAdd(correct, c);
}

__global__ void k_scalars(const float* __restrict__ llh, const int* __restrict__ correct,
                          float* __restrict__ out)
{
    float s = 0.f;
    for (int b = 0; b < NB; ++b) s += llh[b];
    out[0] = -s / (float)NB;
    out[1] = (float)(*correct);
}

// ---------------------------------------------------------------------------
extern "C" void kernel_launch(void* const* d_in, const int* in_sizes, int n_in,
                              void* d_out, int out_size, void* d_ws, size_t ws_size,
                              hipStream_t stream)
{
    const int*   src    = (const int*)d_in[0];
    const int*   label  = (const int*)d_in[1];
    const float* emb    = (const float*)d_in[2];
    const float* Wih_f  = (const float*)d_in[3];
    const float* Whh_f  = (const float*)d_in[4];
    const float* bih_f  = (const float*)d_in[5];
    const float* bhh_f  = (const float*)d_in[6];
    const float* Wih_b  = (const float*)d_in[7];
    const float* Whh_b  = (const float*)d_in[8];
    const float* bih_b  = (const float*)d_in[9];
    const float* bhh_b  = (const float*)d_in[10];
    const float* outW   = (const float*)d_in[11];
    const float* outb   = (const float*)d_in[12];
    const float* start_t= (const float*)d_in[13];
    const float* end_t  = (const float*)d_in[14];
    const float* trans  = (const float*)d_in[15];

    float* Pf      = (float*)d_ws;
    float* Pb      = Pf + (size_t)NV * 768;
    float* hf      = Pb + (size_t)NV * 768;
    float* hb      = hf + (size_t)SEQ * NB * HD;
    float* logitsB = hb + (size_t)SEQ * NB * HD;
    int*   predict = (int*)(logitsB + (size_t)NB * SEQ * NT);
    float* llh     = (float*)(predict + NB * SEQ);
    int*   correct = (int*)(llh + NB);
    float* out     = (float*)d_out;

    hipLaunchKernelGGL(k_init, dim3(1), dim3(64), 0, stream, correct, llh);
    hipLaunchKernelGGL(k_proj, dim3(12, 331), dim3(256), 0, stream,
                       emb, Wih_f, bih_f, Wih_b, bih_b, Pf, Pb);
    hipLaunchKernelGGL(k_gru, dim3(64), dim3(256), 0, stream,
                       Pf, Pb, src, Whh_f, Whh_b, bhh_f, bhh_b, hf, hb);
    hipLaunchKernelGGL(k_logits, dim3(128), dim3(256), 0, stream,
                       hf, hb, outW, outb, logitsB);
    hipLaunchKernelGGL(k_crf, dim3(64), dim3(64), 0, stream,
                       logitsB, label, start_t, end_t, trans, predict, llh);
    hipLaunchKernelGGL(k_final, dim3(128), dim3(256), 0, stream,
                       label, predict, out, correct);
    hipLaunchKernelGGL(k_scalars, dim3(1), dim3(1), 0, stream, llh, correct, out);
}

// Round 7
// 2600.026 us; speedup vs baseline: 4.6084x; 4.6084x over previous
//
#include <hip/hip_runtime.h>
#include <hip/hip_bf16.h>

typedef unsigned char u8;
typedef unsigned short ushort_t;
typedef __bf16 bf16x8 __attribute__((ext_vector_type(8)));
typedef float f32x4 __attribute__((ext_vector_type(4)));

static constexpr int SEQ = 512;
static constexpr int NB  = 64;
static constexpr int HID = 512;
static constexpr int HD  = 256;
static constexpr int NT  = 9;
static constexpr int NV  = 21128;

static __device__ __forceinline__ float b2f(unsigned short u) {
    union { unsigned int i; float f; } v; v.i = ((unsigned int)u) << 16; return v.f;
}
static __device__ __forceinline__ float flo(unsigned int x) {
    union { unsigned int i; float f; } v; v.i = x << 16; return v.f;
}
static __device__ __forceinline__ float fhi(unsigned int x) {
    union { unsigned int i; float f; } v; v.i = x & 0xffff0000u; return v.f;
}
static __device__ __forceinline__ unsigned short f2b(float f) {
    union { float f; unsigned int i; } v; v.f = f;
    unsigned int r = (v.i + 0x7fffu + ((v.i >> 16) & 1u)) >> 16;
    return (unsigned short)r;
}

// ---------------------------------------------------------------------------
// K1: P[v,g] = sum_h E[v,h]*W[g,h] + bih[g]  (bf16 output)
// ---------------------------------------------------------------------------
__global__ __launch_bounds__(256)
void k_proj(const float* __restrict__ E, const float* __restrict__ Wf, const float* __restrict__ bf,
            const float* __restrict__ Wb, const float* __restrict__ bb,
            unsigned short* __restrict__ Pf, unsigned short* __restrict__ Pb)
{
    __shared__ float As[32][72];
    __shared__ float Bs[32][136];
    const int gx = blockIdx.x;
    const int vb = blockIdx.y * 64;
    const float* W; const float* bias; unsigned short* P; int gl0;
    if (gx < 6) { W = Wf; bias = bf; P = Pf; gl0 = gx * 128; }
    else        { W = Wb; bias = bb; P = Pb; gl0 = (gx - 6) * 128; }
    const int tid = threadIdx.x;
    const int tx = tid & 15, ty = tid >> 4;
    float acc[4][8];
#pragma unroll
    for (int i = 0; i < 4; ++i)
#pragma unroll
        for (int j = 0; j < 8; ++j) acc[i][j] = 0.f;

    for (int kt = 0; kt < HID; kt += 32) {
#pragma unroll
        for (int i = 0; i < 2; ++i) {
            int f = tid + i * 256;
            int r = f >> 3, kc = (f & 7) * 4;
            int row = vb + r; if (row >= NV) row = NV - 1;
            float4 v = *(const float4*)(E + (size_t)row * HID + kt + kc);
            As[kc + 0][r] = v.x; As[kc + 1][r] = v.y; As[kc + 2][r] = v.z; As[kc + 3][r] = v.w;
        }
#pragma unroll
        for (int i = 0; i < 4; ++i) {
            int f = tid + i * 256;
            int c = f >> 3, kc = (f & 7) * 4;
            float4 v = *(const float4*)(W + (size_t)(gl0 + c) * HID + kt + kc);
            Bs[kc + 0][c] = v.x; Bs[kc + 1][c] = v.y; Bs[kc + 2][c] = v.z; Bs[kc + 3][c] = v.w;
        }
        __syncthreads();
#pragma unroll
        for (int k = 0; k < 32; ++k) {
            float4 a  = *(const float4*)&As[k][ty * 4];
            float4 b0 = *(const float4*)&Bs[k][tx * 8];
            float4 b1 = *(const float4*)&Bs[k][tx * 8 + 4];
            float av[4] = { a.x, a.y, a.z, a.w };
            float bv[8] = { b0.x, b0.y, b0.z, b0.w, b1.x, b1.y, b1.z, b1.w };
#pragma unroll
            for (int i = 0; i < 4; ++i)
#pragma unroll
                for (int j = 0; j < 8; ++j) acc[i][j] = fmaf(av[i], bv[j], acc[i][j]);
        }
        __syncthreads();
    }
#pragma unroll
    for (int i = 0; i < 4; ++i) {
        int row = vb + ty * 4 + i;
        if (row < NV) {
#pragma unroll
            for (int j = 0; j < 8; ++j) {
                int gc = gl0 + tx * 8 + j;
                P[(size_t)row * 768 + gc] = f2b(acc[i][j] + bias[gc]);
            }
        }
    }
}

// ---------------------------------------------------------------------------
// K1b: X[s][g][b] = P[src[b,s]][g] (+ bhh[g] for g<512), bf16, both dirs
// ---------------------------------------------------------------------------
__global__ __launch_bounds__(256)
void k_xgather(const unsigned short* __restrict__ Pf, const unsigned short* __restrict__ Pb,
               const int* __restrict__ src,
               const float* __restrict__ bhhF, const float* __restrict__ bhhB,
               unsigned short* __restrict__ Xf, unsigned short* __restrict__ Xb)
{
    __shared__ unsigned short tile[64][72];
    const int bx = blockIdx.x;
    const int s = bx / 12, c = bx % 12;
    const int tid = threadIdx.x;
    const int r = tid >> 2, part = tid & 3;
    const int tok = src[r * SEQ + s];

#pragma unroll
    for (int dir = 0; dir < 2; ++dir) {
        const unsigned short* P = dir ? Pb : Pf;
        const float* bh = dir ? bhhB : bhhF;
        unsigned short* X = dir ? Xb : Xf;
        const unsigned short* sp = P + (size_t)tok * 768 + c * 64 + part * 16;
        uint4 v0 = ((const uint4*)sp)[0];
        uint4 v1 = ((const uint4*)sp)[1];
        ((uint4*)&tile[r][part * 16])[0] = v0;
        ((uint4*)&tile[r][part * 16])[1] = v1;
        __syncthreads();
        int gg = c * 64 + r;
        float bhv = (gg < 512) ? bh[gg] : 0.f;
        union { unsigned short u[16]; uint4 v[2]; } o;
#pragma unroll
        for (int b = 0; b < 16; ++b) {
            unsigned short u = tile[part * 16 + b][r];
            o.u[b] = (gg < 512) ? f2b(b2f(u) + bhv) : u;
        }
        uint4* dst = (uint4*)&X[((size_t)s * 768 + gg) * 64 + part * 16];
        dst[0] = o.v[0]; dst[1] = o.v[1];
        __syncthreads();
    }
}

// ---------------------------------------------------------------------------
// K2: persistent-weight MFMA GRU. 8 WGs = 2 dir x 4 batch-quarters, 512 thr.
// Wave w owns hidden dims [32w,32w+32): gate rows {d, 256+d, 512+d}.
// Whh bf16: kt 0..5 in VGPRs (144/thread), kt 6..7 in LDS (96KB).
// h recurrent state: f32 in registers; broadcast via 8KB bf16 LDS tile.
// ---------------------------------------------------------------------------
__global__ __launch_bounds__(512, 2)
void k_gru2(const unsigned short* __restrict__ Xf, const unsigned short* __restrict__ Xb,
            const float* __restrict__ WhhF, const float* __restrict__ WhhB,
            const float* __restrict__ bhhF, const float* __restrict__ bhhB,
            unsigned short* __restrict__ hF, unsigned short* __restrict__ hB2)
{
    __shared__ unsigned short aL[49152];  // 96KB: kt' in {0,1} x 48 rt x 4 g4 x 16 lanes x 8 k
    __shared__ unsigned short hBuf[4096]; // 8KB:  8 kt x 4 g4 x 16 b x 8 k
    const int dir = blockIdx.x >> 2;
    const int b0  = (blockIdx.x & 3) * 16;
    const int tid = threadIdx.x;
    const int wid = tid >> 6, lane = tid & 63;
    const int l15 = lane & 15, g4 = lane >> 4;
    const unsigned short* X = dir ? Xb : Xf;
    const float* Whh = dir ? WhhB : WhhF;
    const float* bhh = dir ? bhhB : bhhF;
    unsigned short* hout = dir ? hB2 : hF;
    const int bglob = b0 + l15;

    // --- startup: A fragments (kt 0..5) into registers ---
    bf16x8 Areg[3][2][6];
#pragma unroll
    for (int g = 0; g < 3; ++g)
#pragma unroll
        for (int j = 0; j < 2; ++j)
#pragma unroll
            for (int kt = 0; kt < 6; ++kt) {
                int row = g * 256 + wid * 32 + j * 16 + l15;
                const float* p = Whh + (size_t)row * 256 + kt * 32 + g4 * 8;
                float4 lo = *(const float4*)p, hi = *(const float4*)(p + 4);
                bf16x8 v;
                v[0] = (__bf16)lo.x; v[1] = (__bf16)lo.y; v[2] = (__bf16)lo.z; v[3] = (__bf16)lo.w;
                v[4] = (__bf16)hi.x; v[5] = (__bf16)hi.y; v[6] = (__bf16)hi.z; v[7] = (__bf16)hi.w;
                Areg[g][j][kt] = v;
            }
    // --- startup: A fragments (kt 6,7) into LDS (frag-major, conflict-free) ---
    for (int u = tid; u < 6144; u += 512) {
        int s15 = u & 15, unit = u >> 4;
        int g4u = unit & 3, rt = (unit >> 2) % 48, ktp = unit / 192;
        int row = rt * 16 + s15;
        const float* p = Whh + (size_t)row * 256 + (6 + ktp) * 32 + g4u * 8;
#pragma unroll
        for (int j = 0; j < 8; ++j) aL[u * 8 + j] = f2b(p[j]);
    }
    for (int u = tid; u < 4096; u += 512) hBuf[u] = 0;

    float bhhn[2][4];
#pragma unroll
    for (int j = 0; j < 2; ++j)
#pragma unroll
        for (int q = 0; q < 4; ++q)
            bhhn[j][q] = bhh[512 + wid * 32 + j * 16 + g4 * 4 + q];
    float hreg[2][4] = {{0.f,0.f,0.f,0.f},{0.f,0.f,0.f,0.f}};
    __syncthreads();

    // prologue: Xr/Xz for first step
    int s = dir ? (SEQ - 1) : 0;
    unsigned short xrv[8], xzv[8];
#pragma unroll
    for (int j = 0; j < 2; ++j)
#pragma unroll
        for (int q = 0; q < 4; ++q) {
            int d = wid * 32 + j * 16 + g4 * 4 + q;
            xrv[j * 4 + q] = X[((size_t)s * 768 + d) * 64 + bglob];
            xzv[j * 4 + q] = X[((size_t)s * 768 + 256 + d) * 64 + bglob];
        }

#pragma unroll 1
    for (int i = 0; i < SEQ; ++i) {
        s = dir ? (SEQ - 1 - i) : i;
        // acc init: C-in = x-terms (bhh_r/z folded at xgather); accN-in = bhh_n
        f32x4 aR[2], aZ[2], aN[2];
#pragma unroll
        for (int j = 0; j < 2; ++j)
#pragma unroll
            for (int q = 0; q < 4; ++q) {
                aR[j][q] = b2f(xrv[j * 4 + q]);
                aZ[j][q] = b2f(xzv[j * 4 + q]);
                aN[j][q] = bhhn[j][q];
            }
        // xn loads for this step (consumed after MFMA -> latency hidden)
        unsigned short xnv[8];
#pragma unroll
        for (int j = 0; j < 2; ++j)
#pragma unroll
            for (int q = 0; q < 4; ++q) {
                int d = wid * 32 + j * 16 + g4 * 4 + q;
                xnv[j * 4 + q] = X[((size_t)s * 768 + 512 + d) * 64 + bglob];
            }
        // MFMA phase: G = Whh @ h
#pragma unroll
        for (int kt = 0; kt < 8; ++kt) {
            bf16x8 bfrag = *(const bf16x8*)&hBuf[(kt * 4 + g4) * 128 + l15 * 8];
#pragma unroll
            for (int g = 0; g < 3; ++g)
#pragma unroll
                for (int j = 0; j < 2; ++j) {
                    bf16x8 af;
                    if (kt < 6) {
                        af = Areg[g][j][kt];
                    } else {
                        int rt = g * 16 + wid * 2 + j;
                        af = *(const bf16x8*)&aL[((kt - 6) * 192 + rt * 4 + g4) * 128 + l15 * 8];
                    }
                    if (g == 0)      aR[j] = __builtin_amdgcn_mfma_f32_16x16x32_bf16(af, bfrag, aR[j], 0, 0, 0);
                    else if (g == 1) aZ[j] = __builtin_amdgcn_mfma_f32_16x16x32_bf16(af, bfrag, aZ[j], 0, 0, 0);
                    else             aN[j] = __builtin_amdgcn_mfma_f32_16x16x32_bf16(af, bfrag, aN[j], 0, 0, 0);
                }
        }
        __syncthreads();  // bar1: all h-broadcast reads complete

        // prefetch Xr/Xz for next step (in flight during combine)
        int ni = (i < SEQ - 1) ? i + 1 : i;
        int ns = dir ? (SEQ - 1 - ni) : ni;
#pragma unroll
        for (int j = 0; j < 2; ++j)
#pragma unroll
            for (int q = 0; q < 4; ++q) {
                int d = wid * 32 + j * 16 + g4 * 4 + q;
                xrv[j * 4 + q] = X[((size_t)ns * 768 + d) * 64 + bglob];
                xzv[j * 4 + q] = X[((size_t)ns * 768 + 256 + d) * 64 + bglob];
            }
        // combine: gate nonlinearities + state update (f32 state in regs)
#pragma unroll
        for (int j = 0; j < 2; ++j)
#pragma unroll
            for (int q = 0; q < 4; ++q) {
                float r = 1.f / (1.f + __expf(-aR[j][q]));
                float z = 1.f / (1.f + __expf(-aZ[j][q]));
                float n = tanhf(b2f(xnv[j * 4 + q]) + r * aN[j][q]);
                float h = (1.f - z) * n + z * hreg[j][q];
                hreg[j][q] = h;
                int d = wid * 32 + j * 16 + g4 * 4 + q;
                unsigned short hb = f2b(h);
                hBuf[(d >> 5) * 512 + ((d >> 3) & 3) * 128 + l15 * 8 + (d & 7)] = hb;
                hout[((size_t)s * 64 + bglob) * 256 + d] = hb;
            }
        __syncthreads();  // bar2: new h visible for next step
    }
}

// ---------------------------------------------------------------------------
// K3: logits (h is bf16 now)
// ---------------------------------------------------------------------------
__global__ __launch_bounds__(256)
void k_logits(const unsigned short* __restrict__ hf, const unsigned short* __restrict__ hb,
              const float* __restrict__ outW, const float* __restrict__ outb,
              float* __restrict__ logitsB)
{
    __shared__ float Wsm[NT][HID];
    __shared__ float bsm[NT];
    const int tid = threadIdx.x;
    for (int i = tid; i < NT * HID; i += 256) Wsm[i >> 9][i & 511] = outW[i];
    if (tid < NT) bsm[tid] = outb[tid];
    __syncthreads();

    const int sb = blockIdx.x * 256 + tid;
    const int s = sb >> 6, b = sb & 63;
    float acc[NT];
#pragma unroll
    for (int t = 0; t < NT; ++t) acc[t] = bsm[t];
    const uint4* hfp = (const uint4*)(hf + (size_t)sb * HD);
    const uint4* hbp = (const uint4*)(hb + (size_t)sb * HD);
#pragma unroll 4
    for (int k8 = 0; k8 < 32; ++k8) {
        uint4 v = hfp[k8];
        float f[8] = { flo(v.x), fhi(v.x), flo(v.y), fhi(v.y),
                       flo(v.z), fhi(v.z), flo(v.w), fhi(v.w) };
#pragma unroll
        for (int t = 0; t < NT; ++t)
#pragma unroll
            for (int e = 0; e < 8; ++e) acc[t] = fmaf(f[e], Wsm[t][k8 * 8 + e], acc[t]);
    }
#pragma unroll 4
    for (int k8 = 0; k8 < 32; ++k8) {
        uint4 v = hbp[k8];
        float f[8] = { flo(v.x), fhi(v.x), flo(v.y), fhi(v.y),
                       flo(v.z), fhi(v.z), flo(v.w), fhi(v.w) };
#pragma unroll
        for (int t = 0; t < NT; ++t)
#pragma unroll
            for (int e = 0; e < 8; ++e) acc[t] = fmaf(f[e], Wsm[t][HD + k8 * 8 + e], acc[t]);
    }
    float* out = logitsB + ((size_t)b * SEQ + s) * NT;
#pragma unroll
    for (int t = 0; t < NT; ++t) out[t] = acc[t];
}

// ---------------------------------------------------------------------------
// K4: CRF forward (logsumexp) + Viterbi + gold score, one wave per batch
// ---------------------------------------------------------------------------
__global__ __launch_bounds__(64)
void k_crf(const float* __restrict__ logitsB, const int* __restrict__ label,
           const float* __restrict__ startv, const float* __restrict__ endv,
           const float* __restrict__ trans,
           int* __restrict__ predict, float* __restrict__ llh)
{
    __shared__ u8 hist[(SEQ - 1) * NT + 16];
    const int b = blockIdx.x;
    const int l = threadIdx.x;
    const float* em = logitsB + (size_t)b * SEQ * NT;
    const int* lab = label + b * SEQ;

    float tr[NT];
#pragma unroll
    for (int t = 0; t < NT; ++t) tr[t] = (l < NT) ? trans[t * NT + l] : 0.f;

    float numacc = 0.f;
    for (int j = 0; j < 8; ++j) {
        int s = l + j * 64;
        int ls = lab[s];
        numacc += em[s * NT + ls];
        if (s < SEQ - 1) numacc += trans[ls * NT + lab[s + 1]];
        if (s == 0) numacc += startv[ls];
        if (s == SEQ - 1) numacc += endv[ls];
    }
#pragma unroll
    for (int off = 32; off > 0; off >>= 1) numacc += __shfl_down(numacc, off);

    float sc = 0.f, vs = 0.f;
    if (l < NT) { sc = startv[l] + em[l]; vs = sc; }
    float emn = (l < NT) ? em[NT + l] : 0.f;
    for (int s = 1; s < SEQ; ++s) {
        float emc = emn;
        if (s < SEQ - 1) emn = (l < NT) ? em[(s + 1) * NT + l] : 0.f;
        float psv[NT], pvv[NT];
#pragma unroll
        for (int t = 0; t < NT; ++t) {
            psv[t] = __shfl(sc, t) + tr[t];
            pvv[t] = __shfl(vs, t) + tr[t];
        }
        float bestv = pvv[0]; int barg = 0;
#pragma unroll
        for (int t = 1; t < NT; ++t) { if (pvv[t] > bestv) { bestv = pvv[t]; barg = t; } }
        float m = psv[0];
#pragma unroll
        for (int t = 1; t < NT; ++t) m = fmaxf(m, psv[t]);
        float ssum = 0.f;
#pragma unroll
        for (int t = 0; t < NT; ++t) ssum += __expf(psv[t] - m);
        if (l < NT) hist[(s - 1) * NT + l] = (u8)barg;
        sc = m + __logf(ssum) + emc;
        vs = bestv + emc;
    }

    float scg[NT], vsg[NT];
#pragma unroll
    for (int t = 0; t < NT; ++t) {
        scg[t] = __shfl(sc, t) + endv[t];
        vsg[t] = __shfl(vs, t) + endv[t];
    }
    float mm = scg[0];
#pragma unroll
    for (int t = 1; t < NT; ++t) mm = fmaxf(mm, scg[t]);
    float sm = 0.f;
#pragma unroll
    for (int t = 0; t < NT; ++t) sm += __expf(scg[t] - mm);
    float den = mm + __logf(sm);
    float bv = vsg[0]; int last = 0;
#pragma unroll
    for (int t = 1; t < NT; ++t) { if (vsg[t] > bv) { bv = vsg[t]; last = t; } }

    if (l == 0) llh[b] = numacc - den;
    __syncthreads();
    if (l == 0) {
        int cur = last;
        predict[b * SEQ + (SEQ - 1)] = cur;
        for (int s = SEQ - 2; s >= 0; --s) {
            cur = hist[s * NT + cur];
            predict[b * SEQ + s] = cur;
        }
    }
}

// ---------------------------------------------------------------------------
__global__ void k_init(int* c, float* llh)
{
    if (threadIdx.x == 0) *c = 0;
    if (threadIdx.x < NB) llh[threadIdx.x] = 0.f;
}

__global__ __launch_bounds__(256)
void k_final(const int* __restrict__ label, const int* __restrict__ predict,
             float* __restrict__ out, int* __restrict__ correct)
{
    int i = blockIdx.x * 256 + threadIdx.x;
    int lb = label[i];
    int pd = (lb > 0) ? predict[i] : 0;
    out[2 + i] = (float)pd;
    out[2 + NB * SEQ + i] = (float)lb;
    int c = (pd == lb) ? 1 : 0;
#pragma unroll
    for (int off = 32; off > 0; off >>= 1) c += __shfl_down(c, off);
    if ((threadIdx.x & 63) == 0) atomicAdd(correct, c);
}

__global__ void k_scalars(const float* __restrict__ llh, const int* __restrict__ correct,
                          float* __restrict__ out)
{
    float s = 0.f;
    for (int b = 0; b < NB; ++b) s += llh[b];
    out[0] = -s / (float)NB;
    out[1] = (float)(*correct);
}

// ---------------------------------------------------------------------------
extern "C" void kernel_launch(void* const* d_in, const int* in_sizes, int n_in,
                              void* d_out, int out_size, void* d_ws, size_t ws_size,
                              hipStream_t stream)
{
    const int*   src    = (const int*)d_in[0];
    const int*   label  = (const int*)d_in[1];
    const float* emb    = (const float*)d_in[2];
    const float* Wih_f  = (const float*)d_in[3];
    const float* Whh_f  = (const float*)d_in[4];
    const float* bih_f  = (const float*)d_in[5];
    const float* bhh_f  = (const float*)d_in[6];
    const float* Wih_b  = (const float*)d_in[7];
    const float* Whh_b  = (const float*)d_in[8];
    const float* bih_b  = (const float*)d_in[9];
    const float* bhh_b  = (const float*)d_in[10];
    const float* outW   = (const float*)d_in[11];
    const float* outb   = (const float*)d_in[12];
    const float* start_t= (const float*)d_in[13];
    const float* end_t  = (const float*)d_in[14];
    const float* trans  = (const float*)d_in[15];

    // ws layout (bytes):
    //  [0]            Xf  bf16 512*768*64           = 50,331,648
    //  [50,331,648]   Xb  bf16                      = 50,331,648
    //  [100,663,296]  Pf,Pb bf16 (2x 32,452,608)    -- dead after xgather;
    //                 hF,hB2 bf16 (2x 16,777,216) overlay this region
    //  [167,772,160]  logitsB f32 64*512*9          =  4,718,592
    //  [172,490,752]  predict int 32768             =    131,072
    //  [172,621,824]  llh f32 64, correct int
    char* ws = (char*)d_ws;
    unsigned short* Xf = (unsigned short*)ws;
    unsigned short* Xb = (unsigned short*)(ws + 50331648);
    unsigned short* Pf = (unsigned short*)(ws + 100663296);
    unsigned short* Pb = Pf + (size_t)NV * 768;
    unsigned short* hF = (unsigned short*)(ws + 100663296);   // overlays Pf/Pb (P dead)
    unsigned short* hB2= hF + (size_t)SEQ * NB * HD;
    float* logitsB = (float*)(ws + 167772160);
    int*   predict = (int*)(ws + 172490752);
    float* llh     = (float*)(ws + 172621824);
    int*   correct = (int*)(ws + 172622080);
    float* out     = (float*)d_out;

    hipLaunchKernelGGL(k_init, dim3(1), dim3(64), 0, stream, correct, llh);
    hipLaunchKernelGGL(k_proj, dim3(12, 331), dim3(256), 0, stream,
                       emb, Wih_f, bih_f, Wih_b, bih_b, Pf, Pb);
    hipLaunchKernelGGL(k_xgather, dim3(512 * 12), dim3(256), 0, stream,
                       Pf, Pb, src, bhh_f, bhh_b, Xf, Xb);
    hipLaunchKernelGGL(k_gru2, dim3(8), dim3(512), 0, stream,
                       Xf, Xb, Whh_f, Whh_b, bhh_f, bhh_b, hF, hB2);
    hipLaunchKernelGGL(k_logits, dim3(128), dim3(256), 0, stream,
                       hF, hB2, outW, outb, logitsB);
    hipLaunchKernelGGL(k_crf, dim3(64), dim3(64), 0, stream,
                       logitsB, label, start_t, end_t, trans, predict, llh);
    hipLaunchKernelGGL(k_final, dim3(128), dim3(256), 0, stream,
                       label, predict, out, correct);
    hipLaunchKernelGGL(k_scalars, dim3(1), dim3(1), 0, stream, llh, correct, out);
}

// Round 8
// 1543.575 us; speedup vs baseline: 7.7625x; 1.6844x over previous
//
#include <hip/hip_runtime.h>
#include <hip/hip_bf16.h>

typedef unsigned char u8;
typedef __bf16 bf16x8 __attribute__((ext_vector_type(8)));
typedef float f32x4 __attribute__((ext_vector_type(4)));

static constexpr int SEQ = 512;
static constexpr int NB  = 64;
static constexpr int HID = 512;
static constexpr int HD  = 256;
static constexpr int NT  = 9;
static constexpr int NV  = 21128;

static __device__ __forceinline__ float b2f(unsigned short u) {
    union { unsigned int i; float f; } v; v.i = ((unsigned int)u) << 16; return v.f;
}
static __device__ __forceinline__ float flo(unsigned int x) {
    union { unsigned int i; float f; } v; v.i = x << 16; return v.f;
}
static __device__ __forceinline__ float fhi(unsigned int x) {
    union { unsigned int i; float f; } v; v.i = x & 0xffff0000u; return v.f;
}
static __device__ __forceinline__ unsigned short f2b(float f) {   // RNE (cold paths)
    union { float f; unsigned int i; } v; v.f = f;
    unsigned int r = (v.i + 0x7fffu + ((v.i >> 16) & 1u)) >> 16;
    return (unsigned short)r;
}
static __device__ __forceinline__ unsigned int packbf(float a, float b) { // round-half-up (hot)
    union { float f; unsigned int i; } va, vb; va.f = a; vb.f = b;
    return ((va.i + 0x8000u) >> 16) | ((vb.i + 0x8000u) & 0xffff0000u);
}
static __device__ __forceinline__ float rcpf(float x) { return __builtin_amdgcn_rcpf(x); }
static __device__ __forceinline__ float sigmf_(float x) { return rcpf(1.f + __expf(-x)); }
static __device__ __forceinline__ float tanhf_(float y) {
    float t = __expf(-2.f * y);
    return (1.f - t) * rcpf(1.f + t);
}

// ---------------------------------------------------------------------------
// K1: P[v,g] = sum_h E[v,h]*W[g,h] + bih[g]  (bf16 output)
// ---------------------------------------------------------------------------
__global__ __launch_bounds__(256)
void k_proj(const float* __restrict__ E, const float* __restrict__ Wf, const float* __restrict__ bf,
            const float* __restrict__ Wb, const float* __restrict__ bb,
            unsigned short* __restrict__ Pf, unsigned short* __restrict__ Pb)
{
    __shared__ float As[32][72];
    __shared__ float Bs[32][136];
    const int gx = blockIdx.x;
    const int vb = blockIdx.y * 64;
    const float* W; const float* bias; unsigned short* P; int gl0;
    if (gx < 6) { W = Wf; bias = bf; P = Pf; gl0 = gx * 128; }
    else        { W = Wb; bias = bb; P = Pb; gl0 = (gx - 6) * 128; }
    const int tid = threadIdx.x;
    const int tx = tid & 15, ty = tid >> 4;
    float acc[4][8];
#pragma unroll
    for (int i = 0; i < 4; ++i)
#pragma unroll
        for (int j = 0; j < 8; ++j) acc[i][j] = 0.f;

    for (int kt = 0; kt < HID; kt += 32) {
#pragma unroll
        for (int i = 0; i < 2; ++i) {
            int f = tid + i * 256;
            int r = f >> 3, kc = (f & 7) * 4;
            int row = vb + r; if (row >= NV) row = NV - 1;
            float4 v = *(const float4*)(E + (size_t)row * HID + kt + kc);
            As[kc + 0][r] = v.x; As[kc + 1][r] = v.y; As[kc + 2][r] = v.z; As[kc + 3][r] = v.w;
        }
#pragma unroll
        for (int i = 0; i < 4; ++i) {
            int f = tid + i * 256;
            int c = f >> 3, kc = (f & 7) * 4;
            float4 v = *(const float4*)(W + (size_t)(gl0 + c) * HID + kt + kc);
            Bs[kc + 0][c] = v.x; Bs[kc + 1][c] = v.y; Bs[kc + 2][c] = v.z; Bs[kc + 3][c] = v.w;
        }
        __syncthreads();
#pragma unroll
        for (int k = 0; k < 32; ++k) {
            float4 a  = *(const float4*)&As[k][ty * 4];
            float4 b0 = *(const float4*)&Bs[k][tx * 8];
            float4 b1 = *(const float4*)&Bs[k][tx * 8 + 4];
            float av[4] = { a.x, a.y, a.z, a.w };
            float bv[8] = { b0.x, b0.y, b0.z, b0.w, b1.x, b1.y, b1.z, b1.w };
#pragma unroll
            for (int i = 0; i < 4; ++i)
#pragma unroll
                for (int j = 0; j < 8; ++j) acc[i][j] = fmaf(av[i], bv[j], acc[i][j]);
        }
        __syncthreads();
    }
#pragma unroll
    for (int i = 0; i < 4; ++i) {
        int row = vb + ty * 4 + i;
        if (row < NV) {
#pragma unroll
            for (int j = 0; j < 8; ++j) {
                int gc = gl0 + tx * 8 + j;
                P[(size_t)row * 768 + gc] = f2b(acc[i][j] + bias[gc]);
            }
        }
    }
}

// ---------------------------------------------------------------------------
// K1b: thread-major X:  Xt[((db*512+s)*512+tid)*24 + e]
//   e=0..7: r-gate (j0q0..3, j1q0..3), 8..15: z-gate, 16..23: n-gate
//   values = P[tok][gate*256 + d] (+bhh for r,z), d = wid*32 + j*16 + g4*4 + q
// ---------------------------------------------------------------------------
__global__ __launch_bounds__(256)
void k_xgather(const unsigned short* __restrict__ Pf, const unsigned short* __restrict__ Pb,
               const int* __restrict__ src,
               const float* __restrict__ bhhF, const float* __restrict__ bhhB,
               unsigned short* __restrict__ Xt)
{
    const int bx = blockIdx.x;
    const int half = bx & 1;
    const int rest = bx >> 1;
    const int s  = rest & 511;
    const int db = rest >> 9;          // dir*4 + bq
    const int dir = db >> 2, bq = db & 3;
    const int tid = half * 256 + threadIdx.x;
    const int wid = tid >> 6, lane = tid & 63, l15 = lane & 15, g4 = lane >> 4;
    const int b = bq * 16 + l15;
    const int tok = src[b * SEQ + s];
    const unsigned short* row = (dir ? Pb : Pf) + (size_t)tok * 768;
    const float* bh = dir ? bhhB : bhhF;
    const int d0 = wid * 32 + g4 * 4;   // j=0; j=1 adds 16

    uint4 R, Z, N;
    {   // r gate (+bhh)
        uint2 v0 = *(const uint2*)(row + d0);
        uint2 v1 = *(const uint2*)(row + d0 + 16);
        R.x = packbf(b2f((unsigned short)v0.x) + bh[d0 + 0],      b2f((unsigned short)(v0.x >> 16)) + bh[d0 + 1]);
        R.y = packbf(b2f((unsigned short)v0.y) + bh[d0 + 2],      b2f((unsigned short)(v0.y >> 16)) + bh[d0 + 3]);
        R.z = packbf(b2f((unsigned short)v1.x) + bh[d0 + 16],     b2f((unsigned short)(v1.x >> 16)) + bh[d0 + 17]);
        R.w = packbf(b2f((unsigned short)v1.y) + bh[d0 + 18],     b2f((unsigned short)(v1.y >> 16)) + bh[d0 + 19]);
    }
    {   // z gate (+bhh)
        uint2 v0 = *(const uint2*)(row + 256 + d0);
        uint2 v1 = *(const uint2*)(row + 256 + d0 + 16);
        Z.x = packbf(b2f((unsigned short)v0.x) + bh[256 + d0 + 0],  b2f((unsigned short)(v0.x >> 16)) + bh[256 + d0 + 1]);
        Z.y = packbf(b2f((unsigned short)v0.y) + bh[256 + d0 + 2],  b2f((unsigned short)(v0.y >> 16)) + bh[256 + d0 + 3]);
        Z.z = packbf(b2f((unsigned short)v1.x) + bh[256 + d0 + 16], b2f((unsigned short)(v1.x >> 16)) + bh[256 + d0 + 17]);
        Z.w = packbf(b2f((unsigned short)v1.y) + bh[256 + d0 + 18], b2f((unsigned short)(v1.y >> 16)) + bh[256 + d0 + 19]);
    }
    {   // n gate (pass-through)
        uint2 v0 = *(const uint2*)(row + 512 + d0);
        uint2 v1 = *(const uint2*)(row + 512 + d0 + 16);
        N.x = v0.x; N.y = v0.y; N.z = v1.x; N.w = v1.y;
    }
    unsigned short* dst = Xt + ((size_t)(db * 512 + s) * 512 + tid) * 24;
    ((uint4*)dst)[0] = R;
    *(uint4*)(dst + 8)  = Z;
    *(uint4*)(dst + 16) = N;
}

// ---------------------------------------------------------------------------
// K2: persistent-weight MFMA GRU. 8 WGs = 2 dir x 4 batch-quarters, 512 thr.
// Whh bf16: kt 0..5 in VGPR/AGPR (144/thread), kt 6..7 in LDS (96KB).
// hBuf double-buffered (2x8KB) -> single barrier per step.
// X: thread-major, 3x uint4 per step, prefetched one step ahead.
// ---------------------------------------------------------------------------
__global__ __launch_bounds__(512, 1)
void k_gru2(const unsigned short* __restrict__ Xt,
            const float* __restrict__ WhhF, const float* __restrict__ WhhB,
            const float* __restrict__ bhhF, const float* __restrict__ bhhB,
            unsigned short* __restrict__ hF, unsigned short* __restrict__ hB2)
{
    __shared__ unsigned short aL[49152];     // 96KB: kt' {0,1} x 48 rt x 4 g4 x 16 lanes x 8 k
    __shared__ unsigned short hB[2][4096];   // 2 x 8KB: [kb=k>>3][b][k&7]
    const int dir = blockIdx.x >> 2;
    const int bq  = blockIdx.x & 3;
    const int tid = threadIdx.x;
    const int wid = tid >> 6, lane = tid & 63;
    const int l15 = lane & 15, g4 = lane >> 4;
    const float* Whh = dir ? WhhB : WhhF;
    const float* bhh = dir ? bhhB : bhhF;
    unsigned short* hout = dir ? hB2 : hF;
    const int bglob = bq * 16 + l15;

    // A fragments kt 0..5 -> registers
    bf16x8 Areg[3][2][6];
#pragma unroll
    for (int g = 0; g < 3; ++g)
#pragma unroll
        for (int j = 0; j < 2; ++j)
#pragma unroll
            for (int kt = 0; kt < 6; ++kt) {
                int row = g * 256 + wid * 32 + j * 16 + l15;
                const float* p = Whh + (size_t)row * 256 + kt * 32 + g4 * 8;
                float4 lo = *(const float4*)p, hi = *(const float4*)(p + 4);
                bf16x8 v;
                v[0] = (__bf16)lo.x; v[1] = (__bf16)lo.y; v[2] = (__bf16)lo.z; v[3] = (__bf16)lo.w;
                v[4] = (__bf16)hi.x; v[5] = (__bf16)hi.y; v[6] = (__bf16)hi.z; v[7] = (__bf16)hi.w;
                Areg[g][j][kt] = v;
            }
    // A fragments kt 6,7 -> LDS
    for (int u = tid; u < 6144; u += 512) {
        int s15 = u & 15, unit = u >> 4;
        int g4u = unit & 3, rt = (unit >> 2) % 48, ktp = unit / 192;
        int row = rt * 16 + s15;
        const float* p = Whh + (size_t)row * 256 + (6 + ktp) * 32 + g4u * 8;
#pragma unroll
        for (int j = 0; j < 8; ++j) aL[u * 8 + j] = f2b(p[j]);
    }
    for (int u = tid; u < 4096; u += 512) hB[0][u] = 0;

    float bhhn[2][4];
#pragma unroll
    for (int j = 0; j < 2; ++j)
#pragma unroll
        for (int q = 0; q < 4; ++q)
            bhhn[j][q] = bhh[512 + wid * 32 + j * 16 + g4 * 4 + q];
    float hreg[2][4] = {{0.f,0.f,0.f,0.f},{0.f,0.f,0.f,0.f}};

    const unsigned short* xbase = Xt + ((size_t)(dir * 4 + bq) * 512 * 512 + tid) * 24;
    // prologue: load step-0 X
    int s0 = dir ? (SEQ - 1) : 0;
    const unsigned short* xp0 = xbase + (size_t)s0 * 12288;
    uint4 curR = ((const uint4*)xp0)[0];
    uint4 curZ = *(const uint4*)(xp0 + 8);
    uint4 curN = *(const uint4*)(xp0 + 16);
    int pb = 0;
    __syncthreads();

#pragma unroll 1
    for (int i = 0; i < SEQ; ++i) {
        const int s = dir ? (SEQ - 1 - i) : i;
        // acc init: r,z from X (bhh folded), n from bhh_n
        f32x4 aR[2], aZ[2], aN[2];
        aR[0][0]=flo(curR.x); aR[0][1]=fhi(curR.x); aR[0][2]=flo(curR.y); aR[0][3]=fhi(curR.y);
        aR[1][0]=flo(curR.z); aR[1][1]=fhi(curR.z); aR[1][2]=flo(curR.w); aR[1][3]=fhi(curR.w);
        aZ[0][0]=flo(curZ.x); aZ[0][1]=fhi(curZ.x); aZ[0][2]=flo(curZ.y); aZ[0][3]=fhi(curZ.y);
        aZ[1][0]=flo(curZ.z); aZ[1][1]=fhi(curZ.z); aZ[1][2]=flo(curZ.w); aZ[1][3]=fhi(curZ.w);
#pragma unroll
        for (int j = 0; j < 2; ++j)
#pragma unroll
            for (int q = 0; q < 4; ++q) aN[j][q] = bhhn[j][q];

        // prefetch next step X (covered by MFMA + combine + barrier)
        const int ni = (i < SEQ - 1) ? i + 1 : i;
        const int ns = dir ? (SEQ - 1 - ni) : ni;
        const unsigned short* xp = xbase + (size_t)ns * 12288;
        uint4 nxtR = ((const uint4*)xp)[0];
        uint4 nxtZ = *(const uint4*)(xp + 8);
        uint4 nxtN = *(const uint4*)(xp + 16);

        // MFMA: G = Whh @ h
#pragma unroll
        for (int kt = 0; kt < 8; ++kt) {
            bf16x8 bfrag = *(const bf16x8*)&hB[pb][(kt * 4 + g4) * 128 + l15 * 8];
#pragma unroll
            for (int g = 0; g < 3; ++g)
#pragma unroll
                for (int j = 0; j < 2; ++j) {
                    bf16x8 af;
                    if (kt < 6) {
                        af = Areg[g][j][kt];
                    } else {
                        int rt = g * 16 + wid * 2 + j;
                        af = *(const bf16x8*)&aL[((kt - 6) * 192 + rt * 4 + g4) * 128 + l15 * 8];
                    }
                    if (g == 0)      aR[j] = __builtin_amdgcn_mfma_f32_16x16x32_bf16(af, bfrag, aR[j], 0, 0, 0);
                    else if (g == 1) aZ[j] = __builtin_amdgcn_mfma_f32_16x16x32_bf16(af, bfrag, aZ[j], 0, 0, 0);
                    else             aN[j] = __builtin_amdgcn_mfma_f32_16x16x32_bf16(af, bfrag, aN[j], 0, 0, 0);
                }
        }

        // combine + write h (to hB[pb^1] and global)
        const unsigned int xn[2] = { 0u, 0u };  // placeholder to keep structure clear
        (void)xn;
#pragma unroll
        for (int j = 0; j < 2; ++j) {
            float x0 = (j == 0) ? flo(curN.x) : flo(curN.z);
            float x1 = (j == 0) ? fhi(curN.x) : fhi(curN.z);
            float x2 = (j == 0) ? flo(curN.y) : flo(curN.w);
            float x3 = (j == 0) ? fhi(curN.y) : fhi(curN.w);
            float r0 = sigmf_(aR[j][0]), r1 = sigmf_(aR[j][1]), r2 = sigmf_(aR[j][2]), r3 = sigmf_(aR[j][3]);
            float z0 = sigmf_(aZ[j][0]), z1 = sigmf_(aZ[j][1]), z2 = sigmf_(aZ[j][2]), z3 = sigmf_(aZ[j][3]);
            float n0 = tanhf_(fmaf(r0, aN[j][0], x0));
            float n1 = tanhf_(fmaf(r1, aN[j][1], x1));
            float n2 = tanhf_(fmaf(r2, aN[j][2], x2));
            float n3 = tanhf_(fmaf(r3, aN[j][3], x3));
            float h0 = fmaf(z0, hreg[j][0] - n0, n0);
            float h1 = fmaf(z1, hreg[j][1] - n1, n1);
            float h2 = fmaf(z2, hreg[j][2] - n2, n2);
            float h3 = fmaf(z3, hreg[j][3] - n3, n3);
            hreg[j][0] = h0; hreg[j][1] = h1; hreg[j][2] = h2; hreg[j][3] = h3;
            uint2 pk; pk.x = packbf(h0, h1); pk.y = packbf(h2, h3);
            const int k0 = wid * 32 + j * 16 + g4 * 4;     // d for q=0
            const int kb = k0 >> 3;
            *(uint2*)&hB[pb ^ 1][kb * 128 + l15 * 8 + (k0 & 7)] = pk;
            *(uint2*)&hout[((size_t)s * 64 + bglob) * 256 + k0] = pk;
        }
        __syncthreads();
        curR = nxtR; curZ = nxtZ; curN = nxtN;
        pb ^= 1;
    }
}

// ---------------------------------------------------------------------------
// K3: logits (bf16 h)
// ---------------------------------------------------------------------------
__global__ __launch_bounds__(256)
void k_logits(const unsigned short* __restrict__ hf, const unsigned short* __restrict__ hb,
              const float* __restrict__ outW, const float* __restrict__ outb,
              float* __restrict__ logitsB)
{
    __shared__ float Wsm[NT][HID];
    __shared__ float bsm[NT];
    const int tid = threadIdx.x;
    for (int i = tid; i < NT * HID; i += 256) Wsm[i >> 9][i & 511] = outW[i];
    if (tid < NT) bsm[tid] = outb[tid];
    __syncthreads();

    const int sb = blockIdx.x * 256 + tid;
    const int s = sb >> 6, b = sb & 63;
    float acc[NT];
#pragma unroll
    for (int t = 0; t < NT; ++t) acc[t] = bsm[t];
    const uint4* hfp = (const uint4*)(hf + (size_t)sb * HD);
    const uint4* hbp = (const uint4*)(hb + (size_t)sb * HD);
#pragma unroll 4
    for (int k8 = 0; k8 < 32; ++k8) {
        uint4 v = hfp[k8];
        float f[8] = { flo(v.x), fhi(v.x), flo(v.y), fhi(v.y),
                       flo(v.z), fhi(v.z), flo(v.w), fhi(v.w) };
#pragma unroll
        for (int t = 0; t < NT; ++t)
#pragma unroll
            for (int e = 0; e < 8; ++e) acc[t] = fmaf(f[e], Wsm[t][k8 * 8 + e], acc[t]);
    }
#pragma unroll 4
    for (int k8 = 0; k8 < 32; ++k8) {
        uint4 v = hbp[k8];
        float f[8] = { flo(v.x), fhi(v.x), flo(v.y), fhi(v.y),
                       flo(v.z), fhi(v.z), flo(v.w), fhi(v.w) };
#pragma unroll
        for (int t = 0; t < NT; ++t)
#pragma unroll
            for (int e = 0; e < 8; ++e) acc[t] = fmaf(f[e], Wsm[t][HD + k8 * 8 + e], acc[t]);
    }
    float* out = logitsB + ((size_t)b * SEQ + s) * NT;
#pragma unroll
    for (int t = 0; t < NT; ++t) out[t] = acc[t];
}

// ---------------------------------------------------------------------------
// K4: CRF forward + Viterbi + gold score, one wave per batch
// ---------------------------------------------------------------------------
__global__ __launch_bounds__(64)
void k_crf(const float* __restrict__ logitsB, const int* __restrict__ label,
           const float* __restrict__ startv, const float* __restrict__ endv,
           const float* __restrict__ trans,
           int* __restrict__ predict, float* __restrict__ llh)
{
    __shared__ u8 hist[(SEQ - 1) * NT + 16];
    const int b = blockIdx.x;
    const int l = threadIdx.x;
    const float* em = logitsB + (size_t)b * SEQ * NT;
    const int* lab = label + b * SEQ;

    float tr[NT];
#pragma unroll
    for (int t = 0; t < NT; ++t) tr[t] = (l < NT) ? trans[t * NT + l] : 0.f;

    float numacc = 0.f;
    for (int j = 0; j < 8; ++j) {
        int s = l + j * 64;
        int ls = lab[s];
        numacc += em[s * NT + ls];
        if (s < SEQ - 1) numacc += trans[ls * NT + lab[s + 1]];
        if (s == 0) numacc += startv[ls];
        if (s == SEQ - 1) numacc += endv[ls];
    }
#pragma unroll
    for (int off = 32; off > 0; off >>= 1) numacc += __shfl_down(numacc, off);

    float sc = 0.f, vs = 0.f;
    if (l < NT) { sc = startv[l] + em[l]; vs = sc; }
    float emn = (l < NT) ? em[NT + l] : 0.f;
    for (int s = 1; s < SEQ; ++s) {
        float emc = emn;
        if (s < SEQ - 1) emn = (l < NT) ? em[(s + 1) * NT + l] : 0.f;
        float psv[NT], pvv[NT];
#pragma unroll
        for (int t = 0; t < NT; ++t) {
            psv[t] = __shfl(sc, t) + tr[t];
            pvv[t] = __shfl(vs, t) + tr[t];
        }
        float bestv = pvv[0]; int barg = 0;
#pragma unroll
        for (int t = 1; t < NT; ++t) { if (pvv[t] > bestv) { bestv = pvv[t]; barg = t; } }
        float m = psv[0];
#pragma unroll
        for (int t = 1; t < NT; ++t) m = fmaxf(m, psv[t]);
        float ssum = 0.f;
#pragma unroll
        for (int t = 0; t < NT; ++t) ssum += __expf(psv[t] - m);
        if (l < NT) hist[(s - 1) * NT + l] = (u8)barg;
        sc = m + __logf(ssum) + emc;
        vs = bestv + emc;
    }

    float scg[NT], vsg[NT];
#pragma unroll
    for (int t = 0; t < NT; ++t) {
        scg[t] = __shfl(sc, t) + endv[t];
        vsg[t] = __shfl(vs, t) + endv[t];
    }
    float mm = scg[0];
#pragma unroll
    for (int t = 1; t < NT; ++t) mm = fmaxf(mm, scg[t]);
    float sm = 0.f;
#pragma unroll
    for (int t = 0; t < NT; ++t) sm += __expf(scg[t] - mm);
    float den = mm + __logf(sm);
    float bv = vsg[0]; int last = 0;
#pragma unroll
    for (int t = 1; t < NT; ++t) { if (vsg[t] > bv) { bv = vsg[t]; last = t; } }

    if (l == 0) llh[b] = numacc - den;
    __syncthreads();
    if (l == 0) {
        int cur = last;
        predict[b * SEQ + (SEQ - 1)] = cur;
        for (int s = SEQ - 2; s >= 0; --s) {
            cur = hist[s * NT + cur];
            predict[b * SEQ + s] = cur;
        }
    }
}

// ---------------------------------------------------------------------------
__global__ void k_init(int* c, float* llh)
{
    if (threadIdx.x == 0) *c = 0;
    if (threadIdx.x < NB) llh[threadIdx.x] = 0.f;
}

__global__ __launch_bounds__(256)
void k_final(const int* __restrict__ label, const int* __restrict__ predict,
             float* __restrict__ out, int* __restrict__ correct)
{
    int i = blockIdx.x * 256 + threadIdx.x;
    int lb = label[i];
    int pd = (lb > 0) ? predict[i] : 0;
    out[2 + i] = (float)pd;
    out[2 + NB * SEQ + i] = (float)lb;
    int c = (pd == lb) ? 1 : 0;
#pragma unroll
    for (int off = 32; off > 0; off >>= 1) c += __shfl_down(c, off);
    if ((threadIdx.x & 63) == 0) atomicAdd(correct, c);
}

__global__ void k_scalars(const float* __restrict__ llh, const int* __restrict__ correct,
                          float* __restrict__ out)
{
    float s = 0.f;
    for (int b = 0; b < NB; ++b) s += llh[b];
    out[0] = -s / (float)NB;
    out[1] = (float)(*correct);
}

// ---------------------------------------------------------------------------
extern "C" void kernel_launch(void* const* d_in, const int* in_sizes, int n_in,
                              void* d_out, int out_size, void* d_ws, size_t ws_size,
                              hipStream_t stream)
{
    const int*   src    = (const int*)d_in[0];
    const int*   label  = (const int*)d_in[1];
    const float* emb    = (const float*)d_in[2];
    const float* Wih_f  = (const float*)d_in[3];
    const float* Whh_f  = (const float*)d_in[4];
    const float* bih_f  = (const float*)d_in[5];
    const float* bhh_f  = (const float*)d_in[6];
    const float* Wih_b  = (const float*)d_in[7];
    const float* Whh_b  = (const float*)d_in[8];
    const float* bih_b  = (const float*)d_in[9];
    const float* bhh_b  = (const float*)d_in[10];
    const float* outW   = (const float*)d_in[11];
    const float* outb   = (const float*)d_in[12];
    const float* start_t= (const float*)d_in[13];
    const float* end_t  = (const float*)d_in[14];
    const float* trans  = (const float*)d_in[15];

    // ws layout (bytes):
    //  [0]            Xt bf16 thread-major           = 100,663,296
    //  [100,663,296]  Pf,Pb bf16 (2x 32,452,608)     -- dead after xgather;
    //                 hF,hB2 bf16 (2x 16,777,216) overlay this region
    //  [167,772,160]  logitsB f32                    =  4,718,592
    //  [172,490,752]  predict int                    =    131,072
    //  [172,621,824]  llh f32 64, correct int
    char* ws = (char*)d_ws;
    unsigned short* Xt = (unsigned short*)ws;
    unsigned short* Pf = (unsigned short*)(ws + 100663296);
    unsigned short* Pb = Pf + (size_t)NV * 768;
    unsigned short* hF = (unsigned short*)(ws + 100663296);   // overlays P (dead)
    unsigned short* hB2= hF + (size_t)SEQ * NB * HD;
    float* logitsB = (float*)(ws + 167772160);
    int*   predict = (int*)(ws + 172490752);
    float* llh     = (float*)(ws + 172621824);
    int*   correct = (int*)(ws + 172622080);
    float* out     = (float*)d_out;

    hipLaunchKernelGGL(k_init, dim3(1), dim3(64), 0, stream, correct, llh);
    hipLaunchKernelGGL(k_proj, dim3(12, 331), dim3(256), 0, stream,
                       emb, Wih_f, bih_f, Wih_b, bih_b, Pf, Pb);
    hipLaunchKernelGGL(k_xgather, dim3(8192), dim3(256), 0, stream,
                       Pf, Pb, src, bhh_f, bhh_b, Xt);
    hipLaunchKernelGGL(k_gru2, dim3(8), dim3(512), 0, stream,
                       Xt, Whh_f, Whh_b, bhh_f, bhh_b, hF, hB2);
    hipLaunchKernelGGL(k_logits, dim3(128), dim3(256), 0, stream,
                       hF, hB2, outW, outb, logitsB);
    hipLaunchKernelGGL(k_crf, dim3(64), dim3(64), 0, stream,
                       logitsB, label, start_t, end_t, trans, predict, llh);
    hipLaunchKernelGGL(k_final, dim3(128), dim3(256), 0, stream,
                       label, predict, out, correct);
    hipLaunchKernelGGL(k_scalars, dim3(1), dim3(1), 0, stream, llh, correct, out);
}

// Round 9
// 1215.912 us; speedup vs baseline: 9.8543x; 1.2695x over previous
//
#include <hip/hip_runtime.h>
#include <hip/hip_bf16.h>

typedef unsigned char u8;
typedef __bf16 bf16x8 __attribute__((ext_vector_type(8)));
typedef float f32x4 __attribute__((ext_vector_type(4)));

static constexpr int SEQ = 512;
static constexpr int NB  = 64;
static constexpr int HID = 512;
static constexpr int HD  = 256;
static constexpr int NT  = 9;
static constexpr int NV  = 21128;

static __device__ __forceinline__ float b2f(unsigned short u) {
    union { unsigned int i; float f; } v; v.i = ((unsigned int)u) << 16; return v.f;
}
static __device__ __forceinline__ float flo(unsigned int x) {
    union { unsigned int i; float f; } v; v.i = x << 16; return v.f;
}
static __device__ __forceinline__ float fhi(unsigned int x) {
    union { unsigned int i; float f; } v; v.i = x & 0xffff0000u; return v.f;
}
static __device__ __forceinline__ unsigned short f2b(float f) {   // RNE
    union { float f; unsigned int i; } v; v.f = f;
    unsigned int r = (v.i + 0x7fffu + ((v.i >> 16) & 1u)) >> 16;
    return (unsigned short)r;
}
static __device__ __forceinline__ unsigned int packbf(float a, float b) { // round-half-up
    union { float f; unsigned int i; } va, vb; va.f = a; vb.f = b;
    return ((va.i + 0x8000u) >> 16) | ((vb.i + 0x8000u) & 0xffff0000u);
}
static __device__ __forceinline__ float rcpf(float x) { return __builtin_amdgcn_rcpf(x); }
static __device__ __forceinline__ float sigmf_(float x) { return rcpf(1.f + __expf(-x)); }
static __device__ __forceinline__ float tanhf_(float y) {
    float t = __expf(-2.f * y);
    return (1.f - t) * rcpf(1.f + t);
}

// ---------------------------------------------------------------------------
// K1: MFMA GEMM  P[v,g] = sum_h bf16(E[v,h]) * bf16(W[g,h]) + bih[g]
// 128x128 tile, KB=64, 4 waves of 64x64. XOR-swizzled LDS (2-way max).
// grid (12 col-tiles, 166 row-tiles) -- col-fastest keeps W + E panel in L2.
// ---------------------------------------------------------------------------
__global__ __launch_bounds__(256)
void k_proj(const float* __restrict__ E, const float* __restrict__ Wf, const float* __restrict__ bf,
            const float* __restrict__ Wb, const float* __restrict__ bb,
            unsigned short* __restrict__ Pf, unsigned short* __restrict__ Pb)
{
    __shared__ unsigned short As[128 * 64];   // [row][k^swz] bf16, 16KB
    __shared__ unsigned short Bs[128 * 64];   // [col][k^swz] bf16, 16KB
    __shared__ float biasS[128];

    const int gx = blockIdx.x;                // 0..11
    const int vb = blockIdx.y * 128;          // row tile
    const float* W; const float* bias; unsigned short* P; int gl0;
    if (gx < 6) { W = Wf; bias = bf; P = Pf; gl0 = gx * 128; }
    else        { W = Wb; bias = bb; P = Pb; gl0 = (gx - 6) * 128; }

    const int tid  = threadIdx.x;
    const int wid  = tid >> 6, lane = tid & 63;
    const int l15  = lane & 15, g4 = lane >> 4;
    const int wrow = (wid >> 1) * 64, wcol = (wid & 1) * 64;

    if (tid < 128) biasS[tid] = bias[gl0 + tid];

    const int r2 = tid >> 1;                  // 0..127 (row/col within tile)
    const int kc = (tid & 1) * 32;            // k sub-offset
    int eRow = vb + r2; if (eRow >= NV) eRow = NV - 1;
    const float* eBase = E + (size_t)eRow * HID + kc;
    const float* wBase = W + (size_t)(gl0 + r2) * HID + kc;

    f32x4 acc[4][4];
#pragma unroll
    for (int i = 0; i < 4; ++i)
#pragma unroll
        for (int j = 0; j < 4; ++j) acc[i][j] = (f32x4){0.f, 0.f, 0.f, 0.f};

    for (int kt = 0; kt < HID; kt += 64) {
        // stage A (E) and B (W), f32 -> bf16, swizzled groups g^=(row&7)
#pragma unroll
        for (int i = 0; i < 4; ++i) {
            const float4* ep = (const float4*)(eBase + kt) + 2 * i;
            float4 a = ep[0], b = ep[1];
            uint4 pk;
            pk.x = packbf(a.x, a.y); pk.y = packbf(a.z, a.w);
            pk.z = packbf(b.x, b.y); pk.w = packbf(b.z, b.w);
            int g = (((tid & 1) * 4) + i) ^ (r2 & 7);
            *(uint4*)&As[r2 * 64 + g * 8] = pk;
        }
#pragma unroll
        for (int i = 0; i < 4; ++i) {
            const float4* wp = (const float4*)(wBase + kt) + 2 * i;
            float4 a = wp[0], b = wp[1];
            uint4 pk;
            pk.x = packbf(a.x, a.y); pk.y = packbf(a.z, a.w);
            pk.z = packbf(b.x, b.y); pk.w = packbf(b.z, b.w);
            int g = (((tid & 1) * 4) + i) ^ (r2 & 7);
            *(uint4*)&Bs[r2 * 64 + g * 8] = pk;
        }
        __syncthreads();

#pragma unroll
        for (int ktb = 0; ktb < 2; ++ktb) {
            bf16x8 af[4], bfg[4];
#pragma unroll
            for (int mi = 0; mi < 4; ++mi) {
                int arow = wrow + mi * 16 + l15;
                int ag = (ktb * 4 + g4) ^ (arow & 7);
                af[mi] = *(const bf16x8*)&As[arow * 64 + ag * 8];
            }
#pragma unroll
            for (int ni = 0; ni < 4; ++ni) {
                int brow = wcol + ni * 16 + l15;
                int bg = (ktb * 4 + g4) ^ (brow & 7);
                bfg[ni] = *(const bf16x8*)&Bs[brow * 64 + bg * 8];
            }
#pragma unroll
            for (int mi = 0; mi < 4; ++mi)
#pragma unroll
                for (int ni = 0; ni < 4; ++ni)
                    acc[mi][ni] = __builtin_amdgcn_mfma_f32_16x16x32_bf16(af[mi], bfg[ni], acc[mi][ni], 0, 0, 0);
        }
        __syncthreads();
    }

    // epilogue: bias + bf16 store. C map: col=lane&15, row=(lane>>4)*4+reg
#pragma unroll
    for (int mi = 0; mi < 4; ++mi)
#pragma unroll
        for (int ni = 0; ni < 4; ++ni) {
            int colL = wcol + ni * 16 + l15;
            int col  = gl0 + colL;
            float bv = biasS[colL];
            f32x4 c = acc[mi][ni];
#pragma unroll
            for (int q = 0; q < 4; ++q) {
                int row = vb + wrow + mi * 16 + g4 * 4 + q;
                if (row < NV) P[(size_t)row * 768 + col] = f2b(c[q] + bv);
            }
        }
}

// ---------------------------------------------------------------------------
// K1b: thread-major X:  Xt[((db*512+s)*512+tid)*24 + e]
//   e=0..7: r-gate, 8..15: z-gate (bhh folded), 16..23: n-gate
// ---------------------------------------------------------------------------
__global__ __launch_bounds__(256)
void k_xgather(const unsigned short* __restrict__ Pf, const unsigned short* __restrict__ Pb,
               const int* __restrict__ src,
               const float* __restrict__ bhhF, const float* __restrict__ bhhB,
               unsigned short* __restrict__ Xt)
{
    const int bx = blockIdx.x;
    const int half = bx & 1;
    const int rest = bx >> 1;
    const int s  = rest & 511;
    const int db = rest >> 9;          // dir*4 + bq
    const int dir = db >> 2, bq = db & 3;
    const int tid = half * 256 + threadIdx.x;
    const int wid = tid >> 6, lane = tid & 63, l15 = lane & 15, g4 = lane >> 4;
    const int b = bq * 16 + l15;
    const int tok = src[b * SEQ + s];
    const unsigned short* row = (dir ? Pb : Pf) + (size_t)tok * 768;
    const float* bh = dir ? bhhB : bhhF;
    const int d0 = wid * 32 + g4 * 4;

    uint4 R, Z, N;
    {
        uint2 v0 = *(const uint2*)(row + d0);
        uint2 v1 = *(const uint2*)(row + d0 + 16);
        R.x = packbf(b2f((unsigned short)v0.x) + bh[d0 + 0],      b2f((unsigned short)(v0.x >> 16)) + bh[d0 + 1]);
        R.y = packbf(b2f((unsigned short)v0.y) + bh[d0 + 2],      b2f((unsigned short)(v0.y >> 16)) + bh[d0 + 3]);
        R.z = packbf(b2f((unsigned short)v1.x) + bh[d0 + 16],     b2f((unsigned short)(v1.x >> 16)) + bh[d0 + 17]);
        R.w = packbf(b2f((unsigned short)v1.y) + bh[d0 + 18],     b2f((unsigned short)(v1.y >> 16)) + bh[d0 + 19]);
    }
    {
        uint2 v0 = *(const uint2*)(row + 256 + d0);
        uint2 v1 = *(const uint2*)(row + 256 + d0 + 16);
        Z.x = packbf(b2f((unsigned short)v0.x) + bh[256 + d0 + 0],  b2f((unsigned short)(v0.x >> 16)) + bh[256 + d0 + 1]);
        Z.y = packbf(b2f((unsigned short)v0.y) + bh[256 + d0 + 2],  b2f((unsigned short)(v0.y >> 16)) + bh[256 + d0 + 3]);
        Z.z = packbf(b2f((unsigned short)v1.x) + bh[256 + d0 + 16], b2f((unsigned short)(v1.x >> 16)) + bh[256 + d0 + 17]);
        Z.w = packbf(b2f((unsigned short)v1.y) + bh[256 + d0 + 18], b2f((unsigned short)(v1.y >> 16)) + bh[256 + d0 + 19]);
    }
    {
        uint2 v0 = *(const uint2*)(row + 512 + d0);
        uint2 v1 = *(const uint2*)(row + 512 + d0 + 16);
        N.x = v0.x; N.y = v0.y; N.z = v1.x; N.w = v1.y;
    }
    unsigned short* dst = Xt + ((size_t)(db * 512 + s) * 512 + tid) * 24;
    ((uint4*)dst)[0] = R;
    *(uint4*)(dst + 8)  = Z;
    *(uint4*)(dst + 16) = N;
}

// ---------------------------------------------------------------------------
// K2: persistent-weight MFMA GRU. 8 WGs = 2 dir x 4 batch-quarters, 512 thr.
// ---------------------------------------------------------------------------
__global__ __launch_bounds__(512, 1)
void k_gru2(const unsigned short* __restrict__ Xt,
            const float* __restrict__ WhhF, const float* __restrict__ WhhB,
            const float* __restrict__ bhhF, const float* __restrict__ bhhB,
            unsigned short* __restrict__ hF, unsigned short* __restrict__ hB2)
{
    __shared__ unsigned short aL[49152];     // 96KB: kt 6,7 A fragments
    __shared__ unsigned short hB[2][4096];   // 2 x 8KB
    const int dir = blockIdx.x >> 2;
    const int bq  = blockIdx.x & 3;
    const int tid = threadIdx.x;
    const int wid = tid >> 6, lane = tid & 63;
    const int l15 = lane & 15, g4 = lane >> 4;
    const float* Whh = dir ? WhhB : WhhF;
    const float* bhh = dir ? bhhB : bhhF;
    unsigned short* hout = dir ? hB2 : hF;
    const int bglob = bq * 16 + l15;

    bf16x8 Areg[3][2][6];
#pragma unroll
    for (int g = 0; g < 3; ++g)
#pragma unroll
        for (int j = 0; j < 2; ++j)
#pragma unroll
            for (int kt = 0; kt < 6; ++kt) {
                int row = g * 256 + wid * 32 + j * 16 + l15;
                const float* p = Whh + (size_t)row * 256 + kt * 32 + g4 * 8;
                float4 lo = *(const float4*)p, hi = *(const float4*)(p + 4);
                bf16x8 v;
                v[0] = (__bf16)lo.x; v[1] = (__bf16)lo.y; v[2] = (__bf16)lo.z; v[3] = (__bf16)lo.w;
                v[4] = (__bf16)hi.x; v[5] = (__bf16)hi.y; v[6] = (__bf16)hi.z; v[7] = (__bf16)hi.w;
                Areg[g][j][kt] = v;
            }
    for (int u = tid; u < 6144; u += 512) {
        int s15 = u & 15, unit = u >> 4;
        int g4u = unit & 3, rt = (unit >> 2) % 48, ktp = unit / 192;
        int row = rt * 16 + s15;
        const float* p = Whh + (size_t)row * 256 + (6 + ktp) * 32 + g4u * 8;
#pragma unroll
        for (int j = 0; j < 8; ++j) aL[u * 8 + j] = f2b(p[j]);
    }
    for (int u = tid; u < 4096; u += 512) hB[0][u] = 0;

    float bhhn[2][4];
#pragma unroll
    for (int j = 0; j < 2; ++j)
#pragma unroll
        for (int q = 0; q < 4; ++q)
            bhhn[j][q] = bhh[512 + wid * 32 + j * 16 + g4 * 4 + q];
    float hreg[2][4] = {{0.f,0.f,0.f,0.f},{0.f,0.f,0.f,0.f}};

    const unsigned short* xbase = Xt + ((size_t)(dir * 4 + bq) * 512 * 512 + tid) * 24;
    int s0 = dir ? (SEQ - 1) : 0;
    const unsigned short* xp0 = xbase + (size_t)s0 * 12288;
    uint4 curR = ((const uint4*)xp0)[0];
    uint4 curZ = *(const uint4*)(xp0 + 8);
    uint4 curN = *(const uint4*)(xp0 + 16);
    int pb = 0;
    __syncthreads();

#pragma unroll 1
    for (int i = 0; i < SEQ; ++i) {
        const int s = dir ? (SEQ - 1 - i) : i;
        f32x4 aR[2], aZ[2], aN[2];
        aR[0][0]=flo(curR.x); aR[0][1]=fhi(curR.x); aR[0][2]=flo(curR.y); aR[0][3]=fhi(curR.y);
        aR[1][0]=flo(curR.z); aR[1][1]=fhi(curR.z); aR[1][2]=flo(curR.w); aR[1][3]=fhi(curR.w);
        aZ[0][0]=flo(curZ.x); aZ[0][1]=fhi(curZ.x); aZ[0][2]=flo(curZ.y); aZ[0][3]=fhi(curZ.y);
        aZ[1][0]=flo(curZ.z); aZ[1][1]=fhi(curZ.z); aZ[1][2]=flo(curZ.w); aZ[1][3]=fhi(curZ.w);
#pragma unroll
        for (int j = 0; j < 2; ++j)
#pragma unroll
            for (int q = 0; q < 4; ++q) aN[j][q] = bhhn[j][q];

        const int ni = (i < SEQ - 1) ? i + 1 : i;
        const int ns = dir ? (SEQ - 1 - ni) : ni;
        const unsigned short* xp = xbase + (size_t)ns * 12288;
        uint4 nxtR = ((const uint4*)xp)[0];
        uint4 nxtZ = *(const uint4*)(xp + 8);
        uint4 nxtN = *(const uint4*)(xp + 16);

#pragma unroll
        for (int kt = 0; kt < 8; ++kt) {
            bf16x8 bfrag = *(const bf16x8*)&hB[pb][(kt * 4 + g4) * 128 + l15 * 8];
#pragma unroll
            for (int g = 0; g < 3; ++g)
#pragma unroll
                for (int j = 0; j < 2; ++j) {
                    bf16x8 af;
                    if (kt < 6) {
                        af = Areg[g][j][kt];
                    } else {
                        int rt = g * 16 + wid * 2 + j;
                        af = *(const bf16x8*)&aL[((kt - 6) * 192 + rt * 4 + g4) * 128 + l15 * 8];
                    }
                    if (g == 0)      aR[j] = __builtin_amdgcn_mfma_f32_16x16x32_bf16(af, bfrag, aR[j], 0, 0, 0);
                    else if (g == 1) aZ[j] = __builtin_amdgcn_mfma_f32_16x16x32_bf16(af, bfrag, aZ[j], 0, 0, 0);
                    else             aN[j] = __builtin_amdgcn_mfma_f32_16x16x32_bf16(af, bfrag, aN[j], 0, 0, 0);
                }
        }

#pragma unroll
        for (int j = 0; j < 2; ++j) {
            float x0 = (j == 0) ? flo(curN.x) : flo(curN.z);
            float x1 = (j == 0) ? fhi(curN.x) : fhi(curN.z);
            float x2 = (j == 0) ? flo(curN.y) : flo(curN.w);
            float x3 = (j == 0) ? fhi(curN.y) : fhi(curN.w);
            float r0 = sigmf_(aR[j][0]), r1 = sigmf_(aR[j][1]), r2 = sigmf_(aR[j][2]), r3 = sigmf_(aR[j][3]);
            float z0 = sigmf_(aZ[j][0]), z1 = sigmf_(aZ[j][1]), z2 = sigmf_(aZ[j][2]), z3 = sigmf_(aZ[j][3]);
            float n0 = tanhf_(fmaf(r0, aN[j][0], x0));
            float n1 = tanhf_(fmaf(r1, aN[j][1], x1));
            float n2 = tanhf_(fmaf(r2, aN[j][2], x2));
            float n3 = tanhf_(fmaf(r3, aN[j][3], x3));
            float h0 = fmaf(z0, hreg[j][0] - n0, n0);
            float h1 = fmaf(z1, hreg[j][1] - n1, n1);
            float h2 = fmaf(z2, hreg[j][2] - n2, n2);
            float h3 = fmaf(z3, hreg[j][3] - n3, n3);
            hreg[j][0] = h0; hreg[j][1] = h1; hreg[j][2] = h2; hreg[j][3] = h3;
            uint2 pk; pk.x = packbf(h0, h1); pk.y = packbf(h2, h3);
            const int k0 = wid * 32 + j * 16 + g4 * 4;
            const int kb = k0 >> 3;
            *(uint2*)&hB[pb ^ 1][kb * 128 + l15 * 8 + (k0 & 7)] = pk;
            *(uint2*)&hout[((size_t)s * 64 + bglob) * 256 + k0] = pk;
        }
        __syncthreads();
        curR = nxtR; curZ = nxtZ; curN = nxtN;
        pb ^= 1;
    }
}

// ---------------------------------------------------------------------------
// K3: logits (bf16 h)
// ---------------------------------------------------------------------------
__global__ __launch_bounds__(256)
void k_logits(const unsigned short* __restrict__ hf, const unsigned short* __restrict__ hb,
              const float* __restrict__ outW, const float* __restrict__ outb,
              float* __restrict__ logitsB)
{
    __shared__ float Wsm[NT][HID];
    __shared__ float bsm[NT];
    const int tid = threadIdx.x;
    for (int i = tid; i < NT * HID; i += 256) Wsm[i >> 9][i & 511] = outW[i];
    if (tid < NT) bsm[tid] = outb[tid];
    __syncthreads();

    const int sb = blockIdx.x * 256 + tid;
    const int s = sb >> 6, b = sb & 63;
    float acc[NT];
#pragma unroll
    for (int t = 0; t < NT; ++t) acc[t] = bsm[t];
    const uint4* hfp = (const uint4*)(hf + (size_t)sb * HD);
    const uint4* hbp = (const uint4*)(hb + (size_t)sb * HD);
#pragma unroll 4
    for (int k8 = 0; k8 < 32; ++k8) {
        uint4 v = hfp[k8];
        float f[8] = { flo(v.x), fhi(v.x), flo(v.y), fhi(v.y),
                       flo(v.z), fhi(v.z), flo(v.w), fhi(v.w) };
#pragma unroll
        for (int t = 0; t < NT; ++t)
#pragma unroll
            for (int e = 0; e < 8; ++e) acc[t] = fmaf(f[e], Wsm[t][k8 * 8 + e], acc[t]);
    }
#pragma unroll 4
    for (int k8 = 0; k8 < 32; ++k8) {
        uint4 v = hbp[k8];
        float f[8] = { flo(v.x), fhi(v.x), flo(v.y), fhi(v.y),
                       flo(v.z), fhi(v.z), flo(v.w), fhi(v.w) };
#pragma unroll
        for (int t = 0; t < NT; ++t)
#pragma unroll
            for (int e = 0; e < 8; ++e) acc[t] = fmaf(f[e], Wsm[t][HD + k8 * 8 + e], acc[t]);
    }
    float* out = logitsB + ((size_t)b * SEQ + s) * NT;
#pragma unroll
    for (int t = 0; t < NT; ++t) out[t] = acc[t];
}

// ---------------------------------------------------------------------------
// K4: CRF forward + Viterbi + gold score, one wave per batch
// ---------------------------------------------------------------------------
__global__ __launch_bounds__(64)
void k_crf(const float* __restrict__ logitsB, const int* __restrict__ label,
           const float* __restrict__ startv, const float* __restrict__ endv,
           const float* __restrict__ trans,
           int* __restrict__ predict, float* __restrict__ llh)
{
    __shared__ u8 hist[(SEQ - 1) * NT + 16];
    const int b = blockIdx.x;
    const int l = threadIdx.x;
    const float* em = logitsB + (size_t)b * SEQ * NT;
    const int* lab = label + b * SEQ;

    float tr[NT];
#pragma unroll
    for (int t = 0; t < NT; ++t) tr[t] = (l < NT) ? trans[t * NT + l] : 0.f;

    float numacc = 0.f;
    for (int j = 0; j < 8; ++j) {
        int s = l + j * 64;
        int ls = lab[s];
        numacc += em[s * NT + ls];
        if (s < SEQ - 1) numacc += trans[ls * NT + lab[s + 1]];
        if (s == 0) numacc += startv[ls];
        if (s == SEQ - 1) numacc += endv[ls];
    }
#pragma unroll
    for (int off = 32; off > 0; off >>= 1) numacc += __shfl_down(numacc, off);

    float sc = 0.f, vs = 0.f;
    if (l < NT) { sc = startv[l] + em[l]; vs = sc; }
    float emn = (l < NT) ? em[NT + l] : 0.f;
    for (int s = 1; s < SEQ; ++s) {
        float emc = emn;
        if (s < SEQ - 1) emn = (l < NT) ? em[(s + 1) * NT + l] : 0.f;
        float psv[NT], pvv[NT];
#pragma unroll
        for (int t = 0; t < NT; ++t) {
            psv[t] = __shfl(sc, t) + tr[t];
            pvv[t] = __shfl(vs, t) + tr[t];
        }
        float bestv = pvv[0]; int barg = 0;
#pragma unroll
        for (int t = 1; t < NT; ++t) { if (pvv[t] > bestv) { bestv = pvv[t]; barg = t; } }
        float m = psv[0];
#pragma unroll
        for (int t = 1; t < NT; ++t) m = fmaxf(m, psv[t]);
        float ssum = 0.f;
#pragma unroll
        for (int t = 0; t < NT; ++t) ssum += __expf(psv[t] - m);
        if (l < NT) hist[(s - 1) * NT + l] = (u8)barg;
        sc = m + __logf(ssum) + emc;
        vs = bestv + emc;
    }

    float scg[NT], vsg[NT];
#pragma unroll
    for (int t = 0; t < NT; ++t) {
        scg[t] = __shfl(sc, t) + endv[t];
        vsg[t] = __shfl(vs, t) + endv[t];
    }
    float mm = scg[0];
#pragma unroll
    for (int t = 1; t < NT; ++t) mm = fmaxf(mm, scg[t]);
    float sm = 0.f;
#pragma unroll
    for (int t = 0; t < NT; ++t) sm += __expf(scg[t] - mm);
    float den = mm + __logf(sm);
    float bv = vsg[0]; int last = 0;
#pragma unroll
    for (int t = 1; t < NT; ++t) { if (vsg[t] > bv) { bv = vsg[t]; last = t; } }

    if (l == 0) llh[b] = numacc - den;
    __syncthreads();
    if (l == 0) {
        int cur = last;
        predict[b * SEQ + (SEQ - 1)] = cur;
        for (int s = SEQ - 2; s >= 0; --s) {
            cur = hist[s * NT + cur];
            predict[b * SEQ + s] = cur;
        }
    }
}

// ---------------------------------------------------------------------------
__global__ void k_init(int* c, float* llh)
{
    if (threadIdx.x == 0) *c = 0;
    if (threadIdx.x < NB) llh[threadIdx.x] = 0.f;
}

__global__ __launch_bounds__(256)
void k_final(const int* __restrict__ label, const int* __restrict__ predict,
             float* __restrict__ out, int* __restrict__ correct)
{
    int i = blockIdx.x * 256 + threadIdx.x;
    int lb = label[i];
    int pd = (lb > 0) ? predict[i] : 0;
    out[2 + i] = (float)pd;
    out[2 + NB * SEQ + i] = (float)lb;
    int c = (pd == lb) ? 1 : 0;
#pragma unroll
    for (int off = 32; off > 0; off >>= 1) c += __shfl_down(c, off);
    if ((threadIdx.x & 63) == 0) atomicAdd(correct, c);
}

__global__ void k_scalars(const float* __restrict__ llh, const int* __restrict__ correct,
                          float* __restrict__ out)
{
    float s = 0.f;
    for (int b = 0; b < NB; ++b) s += llh[b];
    out[0] = -s / (float)NB;
    out[1] = (float)(*correct);
}

// ---------------------------------------------------------------------------
extern "C" void kernel_launch(void* const* d_in, const int* in_sizes, int n_in,
                              void* d_out, int out_size, void* d_ws, size_t ws_size,
                              hipStream_t stream)
{
    const int*   src    = (const int*)d_in[0];
    const int*   label  = (const int*)d_in[1];
    const float* emb    = (const float*)d_in[2];
    const float* Wih_f  = (const float*)d_in[3];
    const float* Whh_f  = (const float*)d_in[4];
    const float* bih_f  = (const float*)d_in[5];
    const float* bhh_f  = (const float*)d_in[6];
    const float* Wih_b  = (const float*)d_in[7];
    const float* Whh_b  = (const float*)d_in[8];
    const float* bih_b  = (const float*)d_in[9];
    const float* bhh_b  = (const float*)d_in[10];
    const float* outW   = (const float*)d_in[11];
    const float* outb   = (const float*)d_in[12];
    const float* start_t= (const float*)d_in[13];
    const float* end_t  = (const float*)d_in[14];
    const float* trans  = (const float*)d_in[15];

    char* ws = (char*)d_ws;
    unsigned short* Xt = (unsigned short*)ws;                      // 100,663,296 B
    unsigned short* Pf = (unsigned short*)(ws + 100663296);
    unsigned short* Pb = Pf + (size_t)NV * 768;
    unsigned short* hF = (unsigned short*)(ws + 100663296);        // overlays P (dead after xgather)
    unsigned short* hB2= hF + (size_t)SEQ * NB * HD;
    float* logitsB = (float*)(ws + 167772160);
    int*   predict = (int*)(ws + 172490752);
    float* llh     = (float*)(ws + 172621824);
    int*   correct = (int*)(ws + 172622080);
    float* out     = (float*)d_out;

    hipLaunchKernelGGL(k_init, dim3(1), dim3(64), 0, stream, correct, llh);
    hipLaunchKernelGGL(k_proj, dim3(12, 166), dim3(256), 0, stream,
                       emb, Wih_f, bih_f, Wih_b, bih_b, Pf, Pb);
    hipLaunchKernelGGL(k_xgather, dim3(8192), dim3(256), 0, stream,
                       Pf, Pb, src, bhh_f, bhh_b, Xt);
    hipLaunchKernelGGL(k_gru2, dim3(8), dim3(512), 0, stream,
                       Xt, Whh_f, Whh_b, bhh_f, bhh_b, hF, hB2);
    hipLaunchKernelGGL(k_logits, dim3(128), dim3(256), 0, stream,
                       hF, hB2, outW, outb, logitsB);
    hipLaunchKernelGGL(k_crf, dim3(64), dim3(64), 0, stream,
                       logitsB, label, start_t, end_t, trans, predict, llh);
    hipLaunchKernelGGL(k_final, dim3(128), dim3(256), 0, stream,
                       label, predict, out, correct);
    hipLaunchKernelGGL(k_scalars, dim3(1), dim3(1), 0, stream, llh, correct, out);
}

// Round 10
// 1154.582 us; speedup vs baseline: 10.3778x; 1.0531x over previous
//
#include <hip/hip_runtime.h>
#include <hip/hip_bf16.h>

typedef unsigned char u8;
typedef __bf16 bf16x8 __attribute__((ext_vector_type(8)));
typedef float f32x4 __attribute__((ext_vector_type(4)));

static constexpr int SEQ = 512;
static constexpr int NB  = 64;
static constexpr int HID = 512;
static constexpr int HD  = 256;
static constexpr int NT  = 9;
static constexpr int NV  = 21128;

#define LOG2E  1.44269504f
#define TLOG2E 2.88539008f

static __device__ __forceinline__ float b2f(unsigned short u) {
    union { unsigned int i; float f; } v; v.i = ((unsigned int)u) << 16; return v.f;
}
static __device__ __forceinline__ float flo(unsigned int x) {
    union { unsigned int i; float f; } v; v.i = x << 16; return v.f;
}
static __device__ __forceinline__ float fhi(unsigned int x) {
    union { unsigned int i; float f; } v; v.i = x & 0xffff0000u; return v.f;
}
static __device__ __forceinline__ unsigned short f2b(float f) {   // RNE
    union { float f; unsigned int i; } v; v.f = f;
    unsigned int r = (v.i + 0x7fffu + ((v.i >> 16) & 1u)) >> 16;
    return (unsigned short)r;
}
static __device__ __forceinline__ unsigned int packbf(float a, float b) { // round-half-up
    union { float f; unsigned int i; } va, vb; va.f = a; vb.f = b;
    return ((va.i + 0x8000u) >> 16) | ((vb.i + 0x8000u) & 0xffff0000u);
}
static __device__ __forceinline__ float rcpf(float x) { return __builtin_amdgcn_rcpf(x); }
static __device__ __forceinline__ float ex2(float x) {   // raw v_exp_f32 (2^x)
    float r; asm("v_exp_f32 %0, %1" : "=v"(r) : "v"(x)); return r;
}

// ---------------------------------------------------------------------------
// K1: MFMA GEMM  P[v,g] = sum_h bf16(E[v,h]) * bf16(W[g,h]) + bih[g]
// ---------------------------------------------------------------------------
__global__ __launch_bounds__(256)
void k_proj(const float* __restrict__ E, const float* __restrict__ Wf, const float* __restrict__ bf,
            const float* __restrict__ Wb, const float* __restrict__ bb,
            unsigned short* __restrict__ Pf, unsigned short* __restrict__ Pb)
{
    __shared__ unsigned short As[128 * 64];
    __shared__ unsigned short Bs[128 * 64];
    __shared__ float biasS[128];

    const int gx = blockIdx.x;
    const int vb = blockIdx.y * 128;
    const float* W; const float* bias; unsigned short* P; int gl0;
    if (gx < 6) { W = Wf; bias = bf; P = Pf; gl0 = gx * 128; }
    else        { W = Wb; bias = bb; P = Pb; gl0 = (gx - 6) * 128; }

    const int tid  = threadIdx.x;
    const int wid  = tid >> 6, lane = tid & 63;
    const int l15  = lane & 15, g4 = lane >> 4;
    const int wrow = (wid >> 1) * 64, wcol = (wid & 1) * 64;

    if (tid < 128) biasS[tid] = bias[gl0 + tid];

    const int r2 = tid >> 1;
    const int kc = (tid & 1) * 32;
    int eRow = vb + r2; if (eRow >= NV) eRow = NV - 1;
    const float* eBase = E + (size_t)eRow * HID + kc;
    const float* wBase = W + (size_t)(gl0 + r2) * HID + kc;

    f32x4 acc[4][4];
#pragma unroll
    for (int i = 0; i < 4; ++i)
#pragma unroll
        for (int j = 0; j < 4; ++j) acc[i][j] = (f32x4){0.f, 0.f, 0.f, 0.f};

    for (int kt = 0; kt < HID; kt += 64) {
#pragma unroll
        for (int i = 0; i < 4; ++i) {
            const float4* ep = (const float4*)(eBase + kt) + 2 * i;
            float4 a = ep[0], b = ep[1];
            uint4 pk;
            pk.x = packbf(a.x, a.y); pk.y = packbf(a.z, a.w);
            pk.z = packbf(b.x, b.y); pk.w = packbf(b.z, b.w);
            int g = (((tid & 1) * 4) + i) ^ (r2 & 7);
            *(uint4*)&As[r2 * 64 + g * 8] = pk;
        }
#pragma unroll
        for (int i = 0; i < 4; ++i) {
            const float4* wp = (const float4*)(wBase + kt) + 2 * i;
            float4 a = wp[0], b = wp[1];
            uint4 pk;
            pk.x = packbf(a.x, a.y); pk.y = packbf(a.z, a.w);
            pk.z = packbf(b.x, b.y); pk.w = packbf(b.z, b.w);
            int g = (((tid & 1) * 4) + i) ^ (r2 & 7);
            *(uint4*)&Bs[r2 * 64 + g * 8] = pk;
        }
        __syncthreads();

#pragma unroll
        for (int ktb = 0; ktb < 2; ++ktb) {
            bf16x8 af[4], bfg[4];
#pragma unroll
            for (int mi = 0; mi < 4; ++mi) {
                int arow = wrow + mi * 16 + l15;
                int ag = (ktb * 4 + g4) ^ (arow & 7);
                af[mi] = *(const bf16x8*)&As[arow * 64 + ag * 8];
            }
#pragma unroll
            for (int ni = 0; ni < 4; ++ni) {
                int brow = wcol + ni * 16 + l15;
                int bg = (ktb * 4 + g4) ^ (brow & 7);
                bfg[ni] = *(const bf16x8*)&Bs[brow * 64 + bg * 8];
            }
#pragma unroll
            for (int mi = 0; mi < 4; ++mi)
#pragma unroll
                for (int ni = 0; ni < 4; ++ni)
                    acc[mi][ni] = __builtin_amdgcn_mfma_f32_16x16x32_bf16(af[mi], bfg[ni], acc[mi][ni], 0, 0, 0);
        }
        __syncthreads();
    }

#pragma unroll
    for (int mi = 0; mi < 4; ++mi)
#pragma unroll
        for (int ni = 0; ni < 4; ++ni) {
            int colL = wcol + ni * 16 + l15;
            int col  = gl0 + colL;
            float bv = biasS[colL];
            f32x4 c = acc[mi][ni];
#pragma unroll
            for (int q = 0; q < 4; ++q) {
                int row = vb + wrow + mi * 16 + g4 * 4 + q;
                if (row < NV) P[(size_t)row * 768 + col] = f2b(c[q] + bv);
            }
        }
}

// ---------------------------------------------------------------------------
// K1b: thread-major X for 1024-thread gru:
//   Xt[((db*512+s)*1024 + tid)*12 + {0..3 r, 4..7 z, 8..11 n}]
//   r,z: (P + bhh) * log2e ; n: P * 2log2e   (exp2-domain prescale)
//   thread: w=tid>>6, l15=batch(lane&15), g4=lane>>4, d = w*16+g4*4+q
// ---------------------------------------------------------------------------
__global__ __launch_bounds__(1024)
void k_xgather(const unsigned short* __restrict__ Pf, const unsigned short* __restrict__ Pb,
               const int* __restrict__ src,
               const float* __restrict__ bhhF, const float* __restrict__ bhhB,
               unsigned short* __restrict__ Xt)
{
    const int db = blockIdx.x >> 9;        // dir*4 + bq
    const int s  = blockIdx.x & 511;
    const int dir = db >> 2, bq = db & 3;
    const int tid = threadIdx.x;
    const int w = tid >> 6, lane = tid & 63, l15 = lane & 15, g4 = lane >> 4;
    const int b = bq * 16 + l15;
    const int tok = src[b * SEQ + s];
    const unsigned short* row = (dir ? Pb : Pf) + (size_t)tok * 768;
    const float* bh = dir ? bhhB : bhhF;
    const int d0 = w * 16 + g4 * 4;

    uint2 vr = *(const uint2*)(row + d0);
    uint2 vz = *(const uint2*)(row + 256 + d0);
    uint2 vn = *(const uint2*)(row + 512 + d0);
    float4 br = *(const float4*)(bh + d0);
    float4 bz = *(const float4*)(bh + 256 + d0);

    uint2 R, Z, N;
    R.x = packbf((b2f((unsigned short)vr.x) + br.x) * LOG2E, (b2f((unsigned short)(vr.x >> 16)) + br.y) * LOG2E);
    R.y = packbf((b2f((unsigned short)vr.y) + br.z) * LOG2E, (b2f((unsigned short)(vr.y >> 16)) + br.w) * LOG2E);
    Z.x = packbf((b2f((unsigned short)vz.x) + bz.x) * LOG2E, (b2f((unsigned short)(vz.x >> 16)) + bz.y) * LOG2E);
    Z.y = packbf((b2f((unsigned short)vz.y) + bz.z) * LOG2E, (b2f((unsigned short)(vz.y >> 16)) + bz.w) * LOG2E);
    N.x = packbf(b2f((unsigned short)vn.x) * TLOG2E, b2f((unsigned short)(vn.x >> 16)) * TLOG2E);
    N.y = packbf(b2f((unsigned short)vn.y) * TLOG2E, b2f((unsigned short)(vn.y >> 16)) * TLOG2E);

    unsigned short* dst = Xt + ((size_t)(db * 512 + s) * 1024 + tid) * 12;
    *(uint2*)(dst)     = R;
    *(uint2*)(dst + 4) = Z;
    *(uint2*)(dst + 8) = N;
}

// ---------------------------------------------------------------------------
// K2: persistent-weight MFMA GRU. 8 WGs x 1024 threads (16 waves x 16 dims).
// Whh bf16 (exp2-prescaled): kt 0..5 in VGPR (72/thread), kt 6..7 in LDS.
// 4 elements/thread combine; 4 waves/SIMD for latency hiding.
// ---------------------------------------------------------------------------
__global__ __launch_bounds__(1024, 4)
void k_gru2(const unsigned short* __restrict__ Xt,
            const float* __restrict__ WhhF, const float* __restrict__ WhhB,
            const float* __restrict__ bhhF, const float* __restrict__ bhhB,
            unsigned short* __restrict__ hF, unsigned short* __restrict__ hB2)
{
    __shared__ unsigned short aL[49152];     // 96KB: kt 6,7 A fragments
    __shared__ unsigned short hB[2][4096];   // 2 x 8KB: [kb][batch][k&7]
    const int dir = blockIdx.x >> 2;
    const int bq  = blockIdx.x & 3;
    const int tid = threadIdx.x;
    const int w = tid >> 6, lane = tid & 63;
    const int l15 = lane & 15, g4 = lane >> 4;
    const float* Whh = dir ? WhhB : WhhF;
    const float* bhh = dir ? bhhB : bhhF;
    unsigned short* hout = dir ? hB2 : hF;
    const int bglob = bq * 16 + l15;

    // A fragments kt 0..5 -> registers (16 dims per wave), prescaled
    bf16x8 Areg[3][6];
#pragma unroll
    for (int g = 0; g < 3; ++g) {
        const float sc = (g == 2) ? TLOG2E : LOG2E;
#pragma unroll
        for (int kt = 0; kt < 6; ++kt) {
            int row = g * 256 + w * 16 + l15;
            const float* p = Whh + (size_t)row * 256 + kt * 32 + g4 * 8;
            float4 lo = *(const float4*)p, hi = *(const float4*)(p + 4);
            bf16x8 v;
            v[0] = (__bf16)(lo.x * sc); v[1] = (__bf16)(lo.y * sc);
            v[2] = (__bf16)(lo.z * sc); v[3] = (__bf16)(lo.w * sc);
            v[4] = (__bf16)(hi.x * sc); v[5] = (__bf16)(hi.y * sc);
            v[6] = (__bf16)(hi.z * sc); v[7] = (__bf16)(hi.w * sc);
            Areg[g][kt] = v;
        }
    }
    // A fragments kt 6,7 -> LDS, prescaled per row
    for (int u = tid; u < 6144; u += 1024) {
        int s15 = u & 15, unit = u >> 4;
        int g4u = unit & 3, rt = (unit >> 2) % 48, ktp = unit / 192;
        int row = rt * 16 + s15;
        float sc = (row >= 512) ? TLOG2E : LOG2E;
        const float* p = Whh + (size_t)row * 256 + (6 + ktp) * 32 + g4u * 8;
#pragma unroll
        for (int j = 0; j < 8; ++j) aL[u * 8 + j] = f2b(p[j] * sc);
    }
    for (int u = tid; u < 4096; u += 1024) hB[0][u] = 0;

    float bhhn[4];
#pragma unroll
    for (int q = 0; q < 4; ++q) bhhn[q] = bhh[512 + w * 16 + g4 * 4 + q] * TLOG2E;
    float hreg[4] = {0.f, 0.f, 0.f, 0.f};

    const unsigned short* xbase = Xt + (size_t)(dir * 4 + bq) * 6291456 + (size_t)tid * 12;
    int s0 = dir ? (SEQ - 1) : 0;
    const unsigned short* xp0 = xbase + (size_t)s0 * 12288;
    uint2 curR = *(const uint2*)(xp0);
    uint2 curZ = *(const uint2*)(xp0 + 4);
    uint2 curN = *(const uint2*)(xp0 + 8);
    int pb = 0;
    __syncthreads();

#pragma unroll 1
    for (int i = 0; i < SEQ; ++i) {
        const int s = dir ? (SEQ - 1 - i) : i;
        f32x4 aR, aZ, aN;
        aR[0] = flo(curR.x); aR[1] = fhi(curR.x); aR[2] = flo(curR.y); aR[3] = fhi(curR.y);
        aZ[0] = flo(curZ.x); aZ[1] = fhi(curZ.x); aZ[2] = flo(curZ.y); aZ[3] = fhi(curZ.y);
#pragma unroll
        for (int q = 0; q < 4; ++q) aN[q] = bhhn[q];

        const int ni = (i < SEQ - 1) ? i + 1 : i;
        const int ns = dir ? (SEQ - 1 - ni) : ni;
        const unsigned short* xp = xbase + (size_t)ns * 12288;
        uint2 nxtR = *(const uint2*)(xp);
        uint2 nxtZ = *(const uint2*)(xp + 4);
        uint2 nxtN = *(const uint2*)(xp + 8);

        // MFMA: G = Whh' @ h
#pragma unroll
        for (int kt = 0; kt < 8; ++kt) {
            bf16x8 bfrag = *(const bf16x8*)&hB[pb][(kt * 4 + g4) * 128 + l15 * 8];
#pragma unroll
            for (int g = 0; g < 3; ++g) {
                bf16x8 af;
                if (kt < 6) {
                    af = Areg[g][kt];
                } else {
                    int rt = g * 16 + w;
                    af = *(const bf16x8*)&aL[((kt - 6) * 192 + rt * 4 + g4) * 128 + l15 * 8];
                }
                if (g == 0)      aR = __builtin_amdgcn_mfma_f32_16x16x32_bf16(af, bfrag, aR, 0, 0, 0);
                else if (g == 1) aZ = __builtin_amdgcn_mfma_f32_16x16x32_bf16(af, bfrag, aZ, 0, 0, 0);
                else             aN = __builtin_amdgcn_mfma_f32_16x16x32_bf16(af, bfrag, aN, 0, 0, 0);
            }
        }

        // combine: exp2-domain sigmoid/tanh, 4 elements
        float xn0 = flo(curN.x), xn1 = fhi(curN.x), xn2 = flo(curN.y), xn3 = fhi(curN.y);
        float r0 = rcpf(1.f + ex2(-aR[0])), r1 = rcpf(1.f + ex2(-aR[1]));
        float r2 = rcpf(1.f + ex2(-aR[2])), r3 = rcpf(1.f + ex2(-aR[3]));
        float z0 = rcpf(1.f + ex2(-aZ[0])), z1 = rcpf(1.f + ex2(-aZ[1]));
        float z2 = rcpf(1.f + ex2(-aZ[2])), z3 = rcpf(1.f + ex2(-aZ[3]));
        float t0 = ex2(-fmaf(r0, aN[0], xn0)), t1 = ex2(-fmaf(r1, aN[1], xn1));
        float t2 = ex2(-fmaf(r2, aN[2], xn2)), t3 = ex2(-fmaf(r3, aN[3], xn3));
        float n0 = (1.f - t0) * rcpf(1.f + t0), n1 = (1.f - t1) * rcpf(1.f + t1);
        float n2 = (1.f - t2) * rcpf(1.f + t2), n3 = (1.f - t3) * rcpf(1.f + t3);
        float h0 = fmaf(z0, hreg[0] - n0, n0);
        float h1 = fmaf(z1, hreg[1] - n1, n1);
        float h2 = fmaf(z2, hreg[2] - n2, n2);
        float h3 = fmaf(z3, hreg[3] - n3, n3);
        hreg[0] = h0; hreg[1] = h1; hreg[2] = h2; hreg[3] = h3;
        uint2 pk; pk.x = packbf(h0, h1); pk.y = packbf(h2, h3);
        const int k0 = w * 16 + g4 * 4;
        *(uint2*)&hB[pb ^ 1][(k0 >> 3) * 128 + l15 * 8 + (k0 & 7)] = pk;
        *(uint2*)&hout[((size_t)s * 64 + bglob) * 256 + k0] = pk;

        __syncthreads();
        curR = nxtR; curZ = nxtZ; curN = nxtN;
        pb ^= 1;
    }
}

// ---------------------------------------------------------------------------
// K3: logits (bf16 h)
// ---------------------------------------------------------------------------
__global__ __launch_bounds__(256)
void k_logits(const unsigned short* __restrict__ hf, const unsigned short* __restrict__ hb,
              const float* __restrict__ outW, const float* __restrict__ outb,
              float* __restrict__ logitsB)
{
    __shared__ float Wsm[NT][HID];
    __shared__ float bsm[NT];
    const int tid = threadIdx.x;
    for (int i = tid; i < NT * HID; i += 256) Wsm[i >> 9][i & 511] = outW[i];
    if (tid < NT) bsm[tid] = outb[tid];
    __syncthreads();

    const int sb = blockIdx.x * 256 + tid;
    const int s = sb >> 6, b = sb & 63;
    float acc[NT];
#pragma unroll
    for (int t = 0; t < NT; ++t) acc[t] = bsm[t];
    const uint4* hfp = (const uint4*)(hf + (size_t)sb * HD);
    const uint4* hbp = (const uint4*)(hb + (size_t)sb * HD);
#pragma unroll 4
    for (int k8 = 0; k8 < 32; ++k8) {
        uint4 v = hfp[k8];
        float f[8] = { flo(v.x), fhi(v.x), flo(v.y), fhi(v.y),
                       flo(v.z), fhi(v.z), flo(v.w), fhi(v.w) };
#pragma unroll
        for (int t = 0; t < NT; ++t)
#pragma unroll
            for (int e = 0; e < 8; ++e) acc[t] = fmaf(f[e], Wsm[t][k8 * 8 + e], acc[t]);
    }
#pragma unroll 4
    for (int k8 = 0; k8 < 32; ++k8) {
        uint4 v = hbp[k8];
        float f[8] = { flo(v.x), fhi(v.x), flo(v.y), fhi(v.y),
                       flo(v.z), fhi(v.z), flo(v.w), fhi(v.w) };
#pragma unroll
        for (int t = 0; t < NT; ++t)
#pragma unroll
            for (int e = 0; e < 8; ++e) acc[t] = fmaf(f[e], Wsm[t][HD + k8 * 8 + e], acc[t]);
    }
    float* out = logitsB + ((size_t)b * SEQ + s) * NT;
#pragma unroll
    for (int t = 0; t < NT; ++t) out[t] = acc[t];
}

// ---------------------------------------------------------------------------
// K4: CRF forward + Viterbi + gold score, one wave per batch
// ---------------------------------------------------------------------------
__global__ __launch_bounds__(64)
void k_crf(const float* __restrict__ logitsB, const int* __restrict__ label,
           const float* __restrict__ startv, const float* __restrict__ endv,
           const float* __restrict__ trans,
           int* __restrict__ predict, float* __restrict__ llh)
{
    __shared__ u8 hist[(SEQ - 1) * NT + 16];
    const int b = blockIdx.x;
    const int l = threadIdx.x;
    const float* em = logitsB + (size_t)b * SEQ * NT;
    const int* lab = label + b * SEQ;

    float tr[NT];
#pragma unroll
    for (int t = 0; t < NT; ++t) tr[t] = (l < NT) ? trans[t * NT + l] : 0.f;

    float numacc = 0.f;
    for (int j = 0; j < 8; ++j) {
        int s = l + j * 64;
        int ls = lab[s];
        numacc += em[s * NT + ls];
        if (s < SEQ - 1) numacc += trans[ls * NT + lab[s + 1]];
        if (s == 0) numacc += startv[ls];
        if (s == SEQ - 1) numacc += endv[ls];
    }
#pragma unroll
    for (int off = 32; off > 0; off >>= 1) numacc += __shfl_down(numacc, off);

    float sc = 0.f, vs = 0.f;
    if (l < NT) { sc = startv[l] + em[l]; vs = sc; }
    float emn = (l < NT) ? em[NT + l] : 0.f;
    for (int s = 1; s < SEQ; ++s) {
        float emc = emn;
        if (s < SEQ - 1) emn = (l < NT) ? em[(s + 1) * NT + l] : 0.f;
        float psv[NT], pvv[NT];
#pragma unroll
        for (int t = 0; t < NT; ++t) {
            psv[t] = __shfl(sc, t) + tr[t];
            pvv[t] = __shfl(vs, t) + tr[t];
        }
        float bestv = pvv[0]; int barg = 0;
#pragma unroll
        for (int t = 1; t < NT; ++t) { if (pvv[t] > bestv) { bestv = pvv[t]; barg = t; } }
        float m = psv[0];
#pragma unroll
        for (int t = 1; t < NT; ++t) m = fmaxf(m, psv[t]);
        float ssum = 0.f;
#pragma unroll
        for (int t = 0; t < NT; ++t) ssum += __expf(psv[t] - m);
        if (l < NT) hist[(s - 1) * NT + l] = (u8)barg;
        sc = m + __logf(ssum) + emc;
        vs = bestv + emc;
    }

    float scg[NT], vsg[NT];
#pragma unroll
    for (int t = 0; t < NT; ++t) {
        scg[t] = __shfl(sc, t) + endv[t];
        vsg[t] = __shfl(vs, t) + endv[t];
    }
    float mm = scg[0];
#pragma unroll
    for (int t = 1; t < NT; ++t) mm = fmaxf(mm, scg[t]);
    float sm = 0.f;
#pragma unroll
    for (int t = 0; t < NT; ++t) sm += __expf(scg[t] - mm);
    float den = mm + __logf(sm);
    float bv = vsg[0]; int last = 0;
#pragma unroll
    for (int t = 1; t < NT; ++t) { if (vsg[t] > bv) { bv = vsg[t]; last = t; } }

    if (l == 0) llh[b] = numacc - den;
    __syncthreads();
    if (l == 0) {
        int cur = last;
        predict[b * SEQ + (SEQ - 1)] = cur;
        for (int s = SEQ - 2; s >= 0; --s) {
            cur = hist[s * NT + cur];
            predict[b * SEQ + s] = cur;
        }
    }
}

// ---------------------------------------------------------------------------
__global__ void k_init(int* c, float* llh)
{
    if (threadIdx.x == 0) *c = 0;
    if (threadIdx.x < NB) llh[threadIdx.x] = 0.f;
}

__global__ __launch_bounds__(256)
void k_final(const int* __restrict__ label, const int* __restrict__ predict,
             float* __restrict__ out, int* __restrict__ correct)
{
    int i = blockIdx.x * 256 + threadIdx.x;
    int lb = label[i];
    int pd = (lb > 0) ? predict[i] : 0;
    out[2 + i] = (float)pd;
    out[2 + NB * SEQ + i] = (float)lb;
    int c = (pd == lb) ? 1 : 0;
#pragma unroll
    for (int off = 32; off > 0; off >>= 1) c += __shfl_down(c, off);
    if ((threadIdx.x & 63) == 0) atomicAdd(correct, c);
}

__global__ void k_scalars(const float* __restrict__ llh, const int* __restrict__ correct,
                          float* __restrict__ out)
{
    float s = 0.f;
    for (int b = 0; b < NB; ++b) s += llh[b];
    out[0] = -s / (float)NB;
    out[1] = (float)(*correct);
}

// ---------------------------------------------------------------------------
extern "C" void kernel_launch(void* const* d_in, const int* in_sizes, int n_in,
                              void* d_out, int out_size, void* d_ws, size_t ws_size,
                              hipStream_t stream)
{
    const int*   src    = (const int*)d_in[0];
    const int*   label  = (const int*)d_in[1];
    const float* emb    = (const float*)d_in[2];
    const float* Wih_f  = (const float*)d_in[3];
    const float* Whh_f  = (const float*)d_in[4];
    const float* bih_f  = (const float*)d_in[5];
    const float* bhh_f  = (const float*)d_in[6];
    const float* Wih_b  = (const float*)d_in[7];
    const float* Whh_b  = (const float*)d_in[8];
    const float* bih_b  = (const float*)d_in[9];
    const float* bhh_b  = (const float*)d_in[10];
    const float* outW   = (const float*)d_in[11];
    const float* outb   = (const float*)d_in[12];
    const float* start_t= (const float*)d_in[13];
    const float* end_t  = (const float*)d_in[14];
    const float* trans  = (const float*)d_in[15];

    char* ws = (char*)d_ws;
    unsigned short* Xt = (unsigned short*)ws;                      // 100,663,296 B
    unsigned short* Pf = (unsigned short*)(ws + 100663296);
    unsigned short* Pb = Pf + (size_t)NV * 768;
    unsigned short* hF = (unsigned short*)(ws + 100663296);        // overlays P (dead after xgather)
    unsigned short* hB2= hF + (size_t)SEQ * NB * HD;
    float* logitsB = (float*)(ws + 167772160);
    int*   predict = (int*)(ws + 172490752);
    float* llh     = (float*)(ws + 172621824);
    int*   correct = (int*)(ws + 172622080);
    float* out     = (float*)d_out;

    hipLaunchKernelGGL(k_init, dim3(1), dim3(64), 0, stream, correct, llh);
    hipLaunchKernelGGL(k_proj, dim3(12, 166), dim3(256), 0, stream,
                       emb, Wih_f, bih_f, Wih_b, bih_b, Pf, Pb);
    hipLaunchKernelGGL(k_xgather, dim3(4096), dim3(1024), 0, stream,
                       Pf, Pb, src, bhh_f, bhh_b, Xt);
    hipLaunchKernelGGL(k_gru2, dim3(8), dim3(1024), 0, stream,
                       Xt, Whh_f, Whh_b, bhh_f, bhh_b, hF, hB2);
    hipLaunchKernelGGL(k_logits, dim3(128), dim3(256), 0, stream,
                       hF, hB2, outW, outb, logitsB);
    hipLaunchKernelGGL(k_crf, dim3(64), dim3(64), 0, stream,
                       logitsB, label, start_t, end_t, trans, predict, llh);
    hipLaunchKernelGGL(k_final, dim3(128), dim3(256), 0, stream,
                       label, predict, out, correct);
    hipLaunchKernelGGL(k_scalars, dim3(1), dim3(1), 0, stream, llh, correct, out);
}